// Round 12
// baseline (640.936 us; speedup 1.0000x reference)
//
#include <hip/hip_runtime.h>
#include <math.h>

// SparseDiffAttn: B=1,H=12,N=2048,D=128, BM=64, top-k=192, static window [c-153,c+153),
// random keys via modern-JAX randint under jax_threefry_partitionable=True:
//   k1 = tf((0,1),(0,0)), k2 = tf((0,1),(0,1))        [fold-like split]
//   bits(k,i) = b1^b2 with (b1,b2) = tf(k,(0,i))      [partitionable random_bits]
//   offset = ((hi%100)*96 + lo%100) % 100; rnd <=> offset==0
// PRECISION NOTE: selection (bs ranking) robust to ~1e-6 rel perturbation
// (fp32 vs fp64 masks identical, R1/R2) but NOT fp16-E ~1e-4 (R10 failed).
// STRUCTURE NOTE (R12): E is never materialized — QK is computed twice
// (pass1: row sums; pass2: weighted colsums -> g_bs 3MB). Cheaper than the
// 402 MB E round-trip. k3 uses an XCD-swizzle so each XCD's L2 holds 1.5
// heads' K/V (3MB < 4MB) instead of thrashing on all 24 MB.
constexpr int Hh   = 12;
constexpr int Nn   = 2048;
constexpr int Dd   = 128;
constexpr int BMq  = 64;
constexpr int QGg  = 32;            // Nn/BMq
constexpr int KSEL = 192;           // 64 * round(0.1*2048/64)
constexpr int CK   = 32;            // key chunk (k3)
constexpr int DC   = 32;            // d-chunk (k1)
constexpr int LSTR = 132;           // padded LDS row stride (floats), 16B-aligned
constexpr float SCALE = 0.08838834764831845f;  // 1/sqrt(128)

// persistent scratch (fully rewritten every launch before any read)
__device__ float          g_lp[(size_t)Hh*Nn*16];   // per-jb partial row sums
__device__ float          g_bs[(size_t)Hh*QGg*Nn];  // colsum scores per group (3 MB)
__device__ unsigned short g_sel[Hh*QGg*Nn];
__device__ int            g_cnt[Hh*QGg];

__device__ __forceinline__ unsigned int rotl32(unsigned int x, int n){
  return (x << n) | (x >> (32 - n));
}

// threefry2x32, 20 rounds, arbitrary key
__device__ __forceinline__ void tf2x32(unsigned int k0, unsigned int k1,
                                       unsigned int x0, unsigned int x1,
                                       unsigned int &o0, unsigned int &o1){
  const unsigned int ks2 = 0x1BD11BDAu ^ k0 ^ k1;
  x0 += k0; x1 += k1;
  x0 += x1; x1 = rotl32(x1,13); x1 ^= x0;
  x0 += x1; x1 = rotl32(x1,15); x1 ^= x0;
  x0 += x1; x1 = rotl32(x1,26); x1 ^= x0;
  x0 += x1; x1 = rotl32(x1, 6); x1 ^= x0;
  x0 += k1; x1 += ks2 + 1u;
  x0 += x1; x1 = rotl32(x1,17); x1 ^= x0;
  x0 += x1; x1 = rotl32(x1,29); x1 ^= x0;
  x0 += x1; x1 = rotl32(x1,16); x1 ^= x0;
  x0 += x1; x1 = rotl32(x1,24); x1 ^= x0;
  x0 += ks2; x1 += k0 + 2u;
  x0 += x1; x1 = rotl32(x1,13); x1 ^= x0;
  x0 += x1; x1 = rotl32(x1,15); x1 ^= x0;
  x0 += x1; x1 = rotl32(x1,26); x1 ^= x0;
  x0 += x1; x1 = rotl32(x1, 6); x1 ^= x0;
  x0 += k0; x1 += k1 + 3u;
  x0 += x1; x1 = rotl32(x1,17); x1 ^= x0;
  x0 += x1; x1 = rotl32(x1,29); x1 ^= x0;
  x0 += x1; x1 = rotl32(x1,16); x1 ^= x0;
  x0 += x1; x1 = rotl32(x1,24); x1 ^= x0;
  x0 += k1; x1 += ks2 + 4u;
  x0 += x1; x1 = rotl32(x1,13); x1 ^= x0;
  x0 += x1; x1 = rotl32(x1,15); x1 ^= x0;
  x0 += x1; x1 = rotl32(x1,26); x1 ^= x0;
  x0 += x1; x1 = rotl32(x1, 6); x1 ^= x0;
  x0 += ks2; x1 += k0 + 5u;
  o0 = x0; o1 = x1;
}

// partitionable-threefry randint(key(1), ..., 0, 100) == 0 for flat element idx
__device__ __forceinline__ bool jax_rand01(unsigned int idx,
                                           unsigned int k1a, unsigned int k1b,
                                           unsigned int k2a, unsigned int k2b){
  unsigned int h0, h1, l0, l1;
  tf2x32(k1a, k1b, 0u, idx, h0, h1);
  tf2x32(k2a, k2b, 0u, idx, l0, l1);
  unsigned int h = h0 ^ h1;
  unsigned int l = l0 ^ l1;
  unsigned int off = ((h % 100u) * 96u + (l % 100u)) % 100u;
  return off == 0u;
}

// ---------------- Kernel 1a (pass1): QK tile -> partial row sums of exp ----------------
__global__ __launch_bounds__(256) void k1a_rowsum(const float* __restrict__ Q,
                                                  const float* __restrict__ K){
  const int bid = blockIdx.x;
  const int jb = bid & 15, gp = (bid >> 4) & 15, h = bid >> 8;
  const int t = threadIdx.x, tx = t & 15, ty = t >> 4;
  __shared__ float Qt[DC][LSTR];
  __shared__ float Kt[DC][LSTR];
  __shared__ float lsum[128][17];

  const int R0 = gp*128, J0 = jb*128;
  const float* Qb = Q + ((size_t)h*Nn + R0)*Dd;
  const float* Kb = K + ((size_t)h*Nn + J0)*Dd;

  float acc[8][8] = {};
  float4 qreg[4], kreg[4];
  #pragma unroll
  for (int it = 0; it < 4; ++it){
    int e = it*256 + t, r = e >> 3, d4 = e & 7;
    qreg[it] = ((const float4*)(Qb + (size_t)r*Dd))[d4];
    kreg[it] = ((const float4*)(Kb + (size_t)r*Dd))[d4];
  }
  for (int c = 0; c < Dd/DC; ++c){
    #pragma unroll
    for (int it = 0; it < 4; ++it){
      int e = it*256 + t, r = e >> 3, d4 = e & 7;
      float4 qv = qreg[it], kv = kreg[it];
      Qt[d4*4+0][r] = qv.x*SCALE; Qt[d4*4+1][r] = qv.y*SCALE;
      Qt[d4*4+2][r] = qv.z*SCALE; Qt[d4*4+3][r] = qv.w*SCALE;
      Kt[d4*4+0][r] = kv.x; Kt[d4*4+1][r] = kv.y;
      Kt[d4*4+2][r] = kv.z; Kt[d4*4+3][r] = kv.w;
    }
    __syncthreads();
    if (c < Dd/DC - 1){
      const int d0 = (c+1)*DC;
      #pragma unroll
      for (int it = 0; it < 4; ++it){
        int e = it*256 + t, r = e >> 3, d4 = e & 7;
        qreg[it] = ((const float4*)(Qb + (size_t)r*Dd + d0))[d4];
        kreg[it] = ((const float4*)(Kb + (size_t)r*Dd + d0))[d4];
      }
    }
    #pragma unroll 8
    for (int dd = 0; dd < DC; ++dd){
      float a[8], b[8];
      *(float4*)&a[0] = *(const float4*)&Qt[dd][ty*8];
      *(float4*)&a[4] = *(const float4*)&Qt[dd][ty*8+4];
      *(float4*)&b[0] = *(const float4*)&Kt[dd][tx*8];
      *(float4*)&b[4] = *(const float4*)&Kt[dd][tx*8+4];
      #pragma unroll
      for (int i = 0; i < 8; ++i)
        #pragma unroll
        for (int j = 0; j < 8; ++j)
          acc[i][j] += a[i]*b[j];
    }
    __syncthreads();
  }

  #pragma unroll
  for (int i = 0; i < 8; ++i){
    float s = 0.f;
    #pragma unroll
    for (int j = 0; j < 8; ++j) s += __expf(acc[i][j]);
    lsum[ty*8+i][tx] = s;
  }
  __syncthreads();
  if (t < 128){
    float s = 0.f;
    #pragma unroll
    for (int x = 0; x < 16; ++x) s += lsum[t][x];
    g_lp[((size_t)h*Nn + R0 + t)*16 + jb] = s;
  }
}

// ---------------- Kernel 1b (pass2): QK tile again -> weighted colsums -> g_bs ----------------
__global__ __launch_bounds__(256) void k1b_bs(const float* __restrict__ Q,
                                              const float* __restrict__ K){
  const int bid = blockIdx.x;
  const int jb = bid & 15, gp = (bid >> 4) & 15, h = bid >> 8;
  const int t = threadIdx.x, tx = t & 15, ty = t >> 4;
  __shared__ float Qt[DC][LSTR];
  __shared__ float Kt[DC][LSTR];
  __shared__ float csum[16][128];   // per-ty partial colsums
  __shared__ float il_s[128];

  const int R0 = gp*128, J0 = jb*128;
  const float* Qb = Q + ((size_t)h*Nn + R0)*Dd;
  const float* Kb = K + ((size_t)h*Nn + J0)*Dd;

  if (t < 128){
    const float* lp = &g_lp[((size_t)h*Nn + R0 + t)*16];
    float s = 0.f;
    #pragma unroll
    for (int x = 0; x < 16; ++x) s += lp[x];
    il_s[t] = 1.0f / s;
  }

  float acc[8][8] = {};
  float4 qreg[4], kreg[4];
  #pragma unroll
  for (int it = 0; it < 4; ++it){
    int e = it*256 + t, r = e >> 3, d4 = e & 7;
    qreg[it] = ((const float4*)(Qb + (size_t)r*Dd))[d4];
    kreg[it] = ((const float4*)(Kb + (size_t)r*Dd))[d4];
  }
  for (int c = 0; c < Dd/DC; ++c){
    #pragma unroll
    for (int it = 0; it < 4; ++it){
      int e = it*256 + t, r = e >> 3, d4 = e & 7;
      float4 qv = qreg[it], kv = kreg[it];
      Qt[d4*4+0][r] = qv.x*SCALE; Qt[d4*4+1][r] = qv.y*SCALE;
      Qt[d4*4+2][r] = qv.z*SCALE; Qt[d4*4+3][r] = qv.w*SCALE;
      Kt[d4*4+0][r] = kv.x; Kt[d4*4+1][r] = kv.y;
      Kt[d4*4+2][r] = kv.z; Kt[d4*4+3][r] = kv.w;
    }
    __syncthreads();
    if (c < Dd/DC - 1){
      const int d0 = (c+1)*DC;
      #pragma unroll
      for (int it = 0; it < 4; ++it){
        int e = it*256 + t, r = e >> 3, d4 = e & 7;
        qreg[it] = ((const float4*)(Qb + (size_t)r*Dd + d0))[d4];
        kreg[it] = ((const float4*)(Kb + (size_t)r*Dd + d0))[d4];
      }
    }
    #pragma unroll 8
    for (int dd = 0; dd < DC; ++dd){
      float a[8], b[8];
      *(float4*)&a[0] = *(const float4*)&Qt[dd][ty*8];
      *(float4*)&a[4] = *(const float4*)&Qt[dd][ty*8+4];
      *(float4*)&b[0] = *(const float4*)&Kt[dd][tx*8];
      *(float4*)&b[4] = *(const float4*)&Kt[dd][tx*8+4];
      #pragma unroll
      for (int i = 0; i < 8; ++i)
        #pragma unroll
        for (int j = 0; j < 8; ++j)
          acc[i][j] += a[i]*b[j];
    }
    __syncthreads();
  }

  // weighted partial colsums over this thread's 8 rows
  float pc[8] = {};
  #pragma unroll
  for (int i = 0; i < 8; ++i){
    float w = il_s[ty*8+i];
    #pragma unroll
    for (int j = 0; j < 8; ++j)
      pc[j] += __expf(acc[i][j]) * w;
  }
  #pragma unroll
  for (int j = 0; j < 8; ++j) csum[ty][tx*8+j] = pc[j];
  __syncthreads();
  // reduce over the 8 ty of each 64-row group; write bs chunk
  {
    const int grp = t >> 7, col = t & 127;   // grp 0: rows 0..63, grp 1: rows 64..127
    float s = 0.f;
    #pragma unroll
    for (int u = 0; u < 8; ++u) s += csum[grp*8+u][col];
    g_bs[((size_t)h*QGg + gp*2 + grp)*Nn + J0 + col] = s;
  }
}

// ---------------- Kernel 2b: top-k + random + static window -> compacted key list ----------------
__global__ __launch_bounds__(256) void k2b_mask(){
  const int bid = blockIdx.x, g = bid % QGg, t = threadIdx.x;
  __shared__ float bsv[Nn];
  __shared__ int red[33];
  __shared__ int csel;
  const float* src = g_bs + (size_t)bid*Nn;
  float mine[8];
  {
    float4 a = *(const float4*)&src[t*4];
    float4 b = *(const float4*)&src[1024 + t*4];
    *(float4*)&bsv[t*4] = a;
    *(float4*)&bsv[1024 + t*4] = b;
    mine[0]=a.x; mine[1]=a.y; mine[2]=a.z; mine[3]=a.w;
    mine[4]=b.x; mine[5]=b.y; mine[6]=b.z; mine[7]=b.w;
  }
  if (t < 33) red[t] = 0;
  if (t == 0) csel = 0;
  __syncthreads();

  unsigned int k1a, k1b, k2a, k2b;
  tf2x32(0u, 1u, 0u, 0u, k1a, k1b);
  tf2x32(0u, 1u, 0u, 1u, k2a, k2b);

  // 192nd-largest via bitwise binary search (positive -> uint order)
  unsigned int prefix = 0u;
  for (int bit = 31; bit >= 0; --bit){
    unsigned int cand = prefix | (1u << bit);
    int c = 0;
    #pragma unroll
    for (int u = 0; u < 8; ++u)
      c += (__float_as_uint(mine[u]) >= cand) ? 1 : 0;
    #pragma unroll
    for (int off = 32; off > 0; off >>= 1) c += __shfl_down(c, off);
    if ((t & 63) == 0) atomicAdd(&red[bit], c);
    __syncthreads();
    if (red[bit] >= KSEL) prefix = cand;
  }
  {
    int cg = 0;
    #pragma unroll
    for (int u = 0; u < 8; ++u)
      cg += (__float_as_uint(mine[u]) > prefix) ? 1 : 0;
    #pragma unroll
    for (int off = 32; off > 0; off >>= 1) cg += __shfl_down(cg, off);
    if ((t & 63) == 0) atomicAdd(&red[32], cg);
  }
  __syncthreads();
  const int need = KSEL - red[32];   // ties taken lowest-index-first (jax top_k)

  const int lo = g*BMq + BMq/2 - 153;   // ws=int(0.15*2048)=307, ws//2=153
  const int hi = g*BMq + BMq/2 + 153;
  const int ssum = ((hi < Nn) ? hi : Nn) - ((lo > 0) ? lo : 0);
  const bool vqg = (ssum + KSEL) < Nn;  // always true at this config

  #pragma unroll
  for (int u = 0; u < 8; ++u){
    int j = (u < 4) ? (t*4 + u) : (1024 + t*4 + u - 4);
    unsigned int bu = __float_as_uint(mine[u]);
    bool topk = bu > prefix;
    if (!topk && bu == prefix){
      int tr = 0;
      for (int jj = 0; jj < j; ++jj)
        tr += (__float_as_uint(bsv[jj]) == prefix) ? 1 : 0;
      topk = (tr < need);
    }
    bool rnd = jax_rand01((unsigned)(bid*Nn + j), k1a, k1b, k2a, k2b);
    bool st  = (j >= lo) && (j < hi);
    bool selb = st || ((rnd || topk) && vqg);
    if (selb){
      int slot = atomicAdd(&csel, 1);
      g_sel[(size_t)bid*Nn + slot] = (unsigned short)j;
    }
  }
  __syncthreads();
  if (t == 0) g_cnt[bid] = csel;
}

// ---------------- Kernel 3: ONE-PASS masked attention, XCD-swizzled for L2 locality ----------------
// Relabel so each XCD (bid%8) owns 96 consecutive work items = 1.5 heads (3MB K/V < 4MB L2).
__global__ __launch_bounds__(256) void k3_attn(const float* __restrict__ Q,
                                               const float* __restrict__ K,
                                               const float* __restrict__ V,
                                               const float* __restrict__ OC,
                                               float* __restrict__ out){
  const int bid0 = blockIdx.x;
  const int w    = (bid0 & 7)*96 + (bid0 >> 3);   // xcd-grouped work index
  const int half = w & 1;
  const int gg   = w >> 1;             // h*QGg + g
  const int h = gg / QGg, g = gg % QGg;
  const int t = threadIdx.x;
  __shared__ float q_s[32][Dd+4];
  __shared__ float kv_s[CK][Dd+4];
  __shared__ float s_s[32][CK+1];
  __shared__ float l_s[32];
  const int c = g_cnt[gg];
  const unsigned short* sel = g_sel + (size_t)gg*Nn;

  const float* qb = Q + ((size_t)h*Nn + (size_t)g*BMq + half*32)*Dd;
  #pragma unroll
  for (int it = 0; it < 4; ++it){
    int e = it*256 + t;                 // 1024 float4s = 32 rows x 32 f4
    int row = e >> 5, c4 = e & 31;
    float4 vq = ((const float4*)qb)[e];
    float4 sv; sv.x = vq.x*SCALE; sv.y = vq.y*SCALE; sv.z = vq.z*SCALE; sv.w = vq.w*SCALE;
    *(float4*)&q_s[row][c4*4] = sv;
  }
  if (t < 32) l_s[t] = 0.0f;
  __syncthreads();

  const int rt = t & 15, kcol = (t >> 4)*2;
  const int d0 = (t >> 4)*8;           // PV column group
  float acc2[2][8] = {};

  for (int c0 = 0; c0 < c; c0 += CK){
    const int cc = ((c - c0) < CK) ? (c - c0) : CK;
    // gather K chunk
    #pragma unroll
    for (int it = 0; it < 4; ++it){
      int e = it*256 + t, row = e >> 5, c4 = e & 31;
      int j = (row < cc) ? (int)sel[c0 + row] : 0;
      *(float4*)&kv_s[row][c4*4] = ((const float4*)(K + ((size_t)h*Nn + j)*Dd))[c4];
    }
    __syncthreads();
    // scores: rows {rt, rt+16} x cols {kcol, kcol+1}
    float a00=0.f, a01=0.f, a10=0.f, a11=0.f;
    #pragma unroll 8
    for (int d = 0; d < Dd; d += 4){
      float4 k0 = *(const float4*)&kv_s[kcol][d];
      float4 k1 = *(const float4*)&kv_s[kcol+1][d];
      float4 q0 = *(const float4*)&q_s[rt][d];
      float4 q1 = *(const float4*)&q_s[rt+16][d];
      a00 += q0.x*k0.x + q0.y*k0.y + q0.z*k0.z + q0.w*k0.w;
      a01 += q0.x*k1.x + q0.y*k1.y + q0.z*k1.z + q0.w*k1.w;
      a10 += q1.x*k0.x + q1.y*k0.y + q1.z*k0.z + q1.w*k0.w;
      a11 += q1.x*k1.x + q1.y*k1.y + q1.z*k1.z + q1.w*k1.w;
    }
    s_s[rt   ][kcol  ] = (kcol   < cc) ? __expf(a00) : 0.f;
    s_s[rt   ][kcol+1] = (kcol+1 < cc) ? __expf(a01) : 0.f;
    s_s[rt+16][kcol  ] = (kcol   < cc) ? __expf(a10) : 0.f;
    s_s[rt+16][kcol+1] = (kcol+1 < cc) ? __expf(a11) : 0.f;
    __syncthreads();
    // row-sum accumulate (l)
    if (t < 32){
      float s = 0.f;
      #pragma unroll
      for (int c2 = 0; c2 < CK; ++c2) s += s_s[t][c2];
      l_s[t] += s;
    }
    // gather V chunk (overwrites kv_s; QK readers already past barrier)
    #pragma unroll
    for (int it = 0; it < 4; ++it){
      int e = it*256 + t, row = e >> 5, c4 = e & 31;
      int j = (row < cc) ? (int)sel[c0 + row] : 0;
      *(float4*)&kv_s[row][c4*4] = ((const float4*)(V + ((size_t)h*Nn + j)*Dd))[c4];
    }
    __syncthreads();
    // PV: rows {rt, rt+16}, cols d0..d0+7
    for (int c2 = 0; c2 < cc; ++c2){
      float p0 = s_s[rt][c2], p1 = s_s[rt+16][c2];
      float4 va = *(const float4*)&kv_s[c2][d0];
      float4 vb = *(const float4*)&kv_s[c2][d0+4];
      acc2[0][0] += p0*va.x; acc2[0][1] += p0*va.y;
      acc2[0][2] += p0*va.z; acc2[0][3] += p0*va.w;
      acc2[0][4] += p0*vb.x; acc2[0][5] += p0*vb.y;
      acc2[0][6] += p0*vb.z; acc2[0][7] += p0*vb.w;
      acc2[1][0] += p1*va.x; acc2[1][1] += p1*va.y;
      acc2[1][2] += p1*va.z; acc2[1][3] += p1*va.w;
      acc2[1][4] += p1*vb.x; acc2[1][5] += p1*vb.y;
      acc2[1][6] += p1*vb.z; acc2[1][7] += p1*vb.w;
    }
    __syncthreads();
  }

  if (t < 32) l_s[t] = 1.0f / l_s[t];
  __syncthreads();

  #pragma unroll
  for (int rr = 0; rr < 2; ++rr){
    const int r = rr*16 + rt;
    const float il = l_s[r];
    size_t o = ((size_t)h*Nn + (size_t)g*BMq + half*32 + r)*Dd + d0;
    float4 ca = *(const float4*)(OC + o);
    float4 cb = *(const float4*)(OC + o + 4);
    float4 ra, rb;
    ra.x = acc2[rr][0]*il + ca.x; ra.y = acc2[rr][1]*il + ca.y;
    ra.z = acc2[rr][2]*il + ca.z; ra.w = acc2[rr][3]*il + ca.w;
    rb.x = acc2[rr][4]*il + cb.x; rb.y = acc2[rr][5]*il + cb.y;
    rb.z = acc2[rr][6]*il + cb.z; rb.w = acc2[rr][7]*il + cb.w;
    *(float4*)(out + o)     = ra;
    *(float4*)(out + o + 4) = rb;
  }
}

extern "C" void kernel_launch(void* const* d_in, const int* in_sizes, int n_in,
                              void* d_out, int out_size, void* d_ws, size_t ws_size,
                              hipStream_t stream) {
  (void)in_sizes; (void)n_in; (void)out_size; (void)d_ws; (void)ws_size;
  const float* Q  = (const float*)d_in[0];
  const float* K  = (const float*)d_in[1];
  const float* V  = (const float*)d_in[2];
  const float* OC = (const float*)d_in[3];
  float* out = (float*)d_out;
  hipLaunchKernelGGL(k1a_rowsum, dim3(Hh*16*16), dim3(256), 0, stream, Q, K);
  hipLaunchKernelGGL(k1b_bs,     dim3(Hh*16*16), dim3(256), 0, stream, Q, K);
  hipLaunchKernelGGL(k2b_mask,   dim3(Hh*QGg),   dim3(256), 0, stream);
  hipLaunchKernelGGL(k3_attn,    dim3(Hh*QGg*2), dim3(256), 0, stream, Q, K, V, OC, out);
}

// Round 13
// 597.646 us; speedup vs baseline: 1.0724x; 1.0724x over previous
//
#include <hip/hip_runtime.h>
#include <math.h>

// SparseDiffAttn: B=1,H=12,N=2048,D=128, BM=64, top-k=192, static window [c-153,c+153),
// random keys via modern-JAX randint under jax_threefry_partitionable=True:
//   k1 = tf((0,1),(0,0)), k2 = tf((0,1),(0,1))        [fold-like split]
//   bits(k,i) = b1^b2 with (b1,b2) = tf(k,(0,i))      [partitionable random_bits]
//   offset = ((hi%100)*96 + lo%100) % 100; rnd <=> offset==0
// PRECISION: selection robust to ~1e-6 rel (fp32==fp64 masks) but NOT fp16-E (R10 failed).
// STRUCTURE (R13): E fp32 materialized (R11) — cheaper than 2x QK recompute (R12 regressed,
// E is L3-resident between k1a and k2). k3: XCD swizzle (R12: FETCH 157->28 MB) makes L2
// reuse structural, so R8's register prefetch is safe again (R8 failed only via L2 thrash).
constexpr int Hh   = 12;
constexpr int Nn   = 2048;
constexpr int Dd   = 128;
constexpr int BMq  = 64;
constexpr int QGg  = 32;            // Nn/BMq
constexpr int KSEL = 192;           // 64 * round(0.1*2048/64)
constexpr int CK   = 32;            // key chunk (k3)
constexpr int DC   = 32;            // d-chunk (k1a)
constexpr int LSTR = 132;           // padded LDS row stride (floats), 16B-aligned
constexpr float SCALE = 0.08838834764831845f;  // 1/sqrt(128)

// persistent scratch (fully rewritten every launch before any read)
__device__ float          g_E [(size_t)Hh*Nn*Nn];   // 201 MB: fp32 exp(score)
__device__ float          g_lp[(size_t)Hh*Nn*16];   // per-jb partial row sums
__device__ unsigned short g_sel[Hh*QGg*Nn];
__device__ int            g_cnt[Hh*QGg];

__device__ __forceinline__ unsigned int rotl32(unsigned int x, int n){
  return (x << n) | (x >> (32 - n));
}

// threefry2x32, 20 rounds, arbitrary key
__device__ __forceinline__ void tf2x32(unsigned int k0, unsigned int k1,
                                       unsigned int x0, unsigned int x1,
                                       unsigned int &o0, unsigned int &o1){
  const unsigned int ks2 = 0x1BD11BDAu ^ k0 ^ k1;
  x0 += k0; x1 += k1;
  x0 += x1; x1 = rotl32(x1,13); x1 ^= x0;
  x0 += x1; x1 = rotl32(x1,15); x1 ^= x0;
  x0 += x1; x1 = rotl32(x1,26); x1 ^= x0;
  x0 += x1; x1 = rotl32(x1, 6); x1 ^= x0;
  x0 += k1; x1 += ks2 + 1u;
  x0 += x1; x1 = rotl32(x1,17); x1 ^= x0;
  x0 += x1; x1 = rotl32(x1,29); x1 ^= x0;
  x0 += x1; x1 = rotl32(x1,16); x1 ^= x0;
  x0 += x1; x1 = rotl32(x1,24); x1 ^= x0;
  x0 += ks2; x1 += k0 + 2u;
  x0 += x1; x1 = rotl32(x1,13); x1 ^= x0;
  x0 += x1; x1 = rotl32(x1,15); x1 ^= x0;
  x0 += x1; x1 = rotl32(x1,26); x1 ^= x0;
  x0 += x1; x1 = rotl32(x1, 6); x1 ^= x0;
  x0 += k0; x1 += k1 + 3u;
  x0 += x1; x1 = rotl32(x1,17); x1 ^= x0;
  x0 += x1; x1 = rotl32(x1,29); x1 ^= x0;
  x0 += x1; x1 = rotl32(x1,16); x1 ^= x0;
  x0 += x1; x1 = rotl32(x1,24); x1 ^= x0;
  x0 += k1; x1 += ks2 + 4u;
  x0 += x1; x1 = rotl32(x1,13); x1 ^= x0;
  x0 += x1; x1 = rotl32(x1,15); x1 ^= x0;
  x0 += x1; x1 = rotl32(x1,26); x1 ^= x0;
  x0 += x1; x1 = rotl32(x1, 6); x1 ^= x0;
  x0 += ks2; x1 += k0 + 5u;
  o0 = x0; o1 = x1;
}

// partitionable-threefry randint(key(1), ..., 0, 100) == 0 for flat element idx
__device__ __forceinline__ bool jax_rand01(unsigned int idx,
                                           unsigned int k1a, unsigned int k1b,
                                           unsigned int k2a, unsigned int k2b){
  unsigned int h0, h1, l0, l1;
  tf2x32(k1a, k1b, 0u, idx, h0, h1);
  tf2x32(k2a, k2b, 0u, idx, l0, l1);
  unsigned int h = h0 ^ h1;
  unsigned int l = l0 ^ l1;
  unsigned int off = ((h % 100u) * 96u + (l % 100u)) % 100u;
  return off == 0u;
}

// ---------------- Kernel 1a: one-pass E=__expf(QK^T*scale) + partial row sums ----------------
__global__ __launch_bounds__(256) void k1a_scores(const float* __restrict__ Q,
                                                  const float* __restrict__ K){
  const int bid = blockIdx.x;
  const int jb = bid & 15, gp = (bid >> 4) & 15, h = bid >> 8;
  const int t = threadIdx.x, tx = t & 15, ty = t >> 4;
  __shared__ float Qt[DC][LSTR];   // transposed, pre-scaled
  __shared__ float Kt[DC][LSTR];   // transposed
  __shared__ float lsum[128][17];

  const int R0 = gp*128, J0 = jb*128;
  const float* Qb = Q + ((size_t)h*Nn + R0)*Dd;
  const float* Kb = K + ((size_t)h*Nn + J0)*Dd;

  float acc[8][8] = {};
  float4 qreg[4], kreg[4];
  #pragma unroll
  for (int it = 0; it < 4; ++it){
    int e = it*256 + t, r = e >> 3, d4 = e & 7;
    qreg[it] = ((const float4*)(Qb + (size_t)r*Dd))[d4];
    kreg[it] = ((const float4*)(Kb + (size_t)r*Dd))[d4];
  }
  for (int c = 0; c < Dd/DC; ++c){
    #pragma unroll
    for (int it = 0; it < 4; ++it){
      int e = it*256 + t, r = e >> 3, d4 = e & 7;
      float4 qv = qreg[it], kv = kreg[it];
      Qt[d4*4+0][r] = qv.x*SCALE; Qt[d4*4+1][r] = qv.y*SCALE;
      Qt[d4*4+2][r] = qv.z*SCALE; Qt[d4*4+3][r] = qv.w*SCALE;
      Kt[d4*4+0][r] = kv.x; Kt[d4*4+1][r] = kv.y;
      Kt[d4*4+2][r] = kv.z; Kt[d4*4+3][r] = kv.w;
    }
    __syncthreads();
    if (c < Dd/DC - 1){
      const int d0 = (c+1)*DC;
      #pragma unroll
      for (int it = 0; it < 4; ++it){
        int e = it*256 + t, r = e >> 3, d4 = e & 7;
        qreg[it] = ((const float4*)(Qb + (size_t)r*Dd + d0))[d4];
        kreg[it] = ((const float4*)(Kb + (size_t)r*Dd + d0))[d4];
      }
    }
    #pragma unroll 8
    for (int dd = 0; dd < DC; ++dd){
      float a[8], b[8];
      *(float4*)&a[0] = *(const float4*)&Qt[dd][ty*8];
      *(float4*)&a[4] = *(const float4*)&Qt[dd][ty*8+4];
      *(float4*)&b[0] = *(const float4*)&Kt[dd][tx*8];
      *(float4*)&b[4] = *(const float4*)&Kt[dd][tx*8+4];
      #pragma unroll
      for (int i = 0; i < 8; ++i)
        #pragma unroll
        for (int j = 0; j < 8; ++j)
          acc[i][j] += a[i]*b[j];
    }
    __syncthreads();
  }

  #pragma unroll
  for (int i = 0; i < 8; ++i){
    const int r = ty*8 + i;
    float ev[8]; float s = 0.f;
    #pragma unroll
    for (int j = 0; j < 8; ++j){ ev[j] = __expf(acc[i][j]); s += ev[j]; }
    lsum[r][tx] = s;
    float4 e0, e1;
    e0.x=ev[0]; e0.y=ev[1]; e0.z=ev[2]; e0.w=ev[3];
    e1.x=ev[4]; e1.y=ev[5]; e1.z=ev[6]; e1.w=ev[7];
    float* Ep = &g_E[((size_t)h*Nn + R0 + r)*Nn + J0 + tx*8];
    *(float4*)Ep = e0;
    *(float4*)(Ep+4) = e1;
  }
  __syncthreads();
  if (t < 128){
    float s = 0.f;
    #pragma unroll
    for (int x = 0; x < 16; ++x) s += lsum[t][x];
    g_lp[((size_t)h*Nn + R0 + t)*16 + jb] = s;
  }
}

// ---------------- Kernel 2: fused bs colsum + top-k + random + static -> key list ----------------
__global__ __launch_bounds__(256) void k2_mask(){
  const int bid = blockIdx.x, h = bid / QGg, g = bid % QGg, t = threadIdx.x;
  __shared__ float bsv[Nn];
  __shared__ float il[BMq];
  __shared__ int red[33];
  __shared__ int csel;
  if (t < BMq){
    const float* lp = &g_lp[((size_t)h*Nn + g*BMq + t)*16];
    float s = 0.f;
    #pragma unroll
    for (int x = 0; x < 16; ++x) s += lp[x];
    il[t] = 1.0f / s;
  }
  if (t < 33) red[t] = 0;
  if (t == 0) csel = 0;
  __syncthreads();

  // bs for this thread's 8 columns: j in {t*4..t*4+3} u {1024+t*4..+3}
  const float* Eb = &g_E[((size_t)h*Nn + (size_t)g*BMq)*Nn];
  const int ja = t*4, jb2 = 1024 + t*4;
  float4 s0 = {0.f,0.f,0.f,0.f}, s1 = {0.f,0.f,0.f,0.f};
  for (int r = 0; r < BMq; r += 8){
    float4 e0[8], e1[8];
    #pragma unroll
    for (int u = 0; u < 8; ++u){
      e0[u] = *(const float4*)(Eb + (size_t)(r+u)*Nn + ja);
      e1[u] = *(const float4*)(Eb + (size_t)(r+u)*Nn + jb2);
    }
    #pragma unroll
    for (int u = 0; u < 8; ++u){
      float w = il[r+u];
      s0.x += e0[u].x*w; s0.y += e0[u].y*w; s0.z += e0[u].z*w; s0.w += e0[u].w*w;
      s1.x += e1[u].x*w; s1.y += e1[u].y*w; s1.z += e1[u].z*w; s1.w += e1[u].w*w;
    }
  }
  *(float4*)&bsv[ja]  = s0;
  *(float4*)&bsv[jb2] = s1;
  float mine[8] = {s0.x,s0.y,s0.z,s0.w, s1.x,s1.y,s1.z,s1.w};
  __syncthreads();

  unsigned int k1a, k1b, k2a, k2b;
  tf2x32(0u, 1u, 0u, 0u, k1a, k1b);
  tf2x32(0u, 1u, 0u, 1u, k2a, k2b);

  // 192nd-largest via bitwise binary search on register values (positive -> uint order)
  unsigned int prefix = 0u;
  for (int bit = 31; bit >= 0; --bit){
    unsigned int cand = prefix | (1u << bit);
    int c = 0;
    #pragma unroll
    for (int u = 0; u < 8; ++u)
      c += (__float_as_uint(mine[u]) >= cand) ? 1 : 0;
    #pragma unroll
    for (int off = 32; off > 0; off >>= 1) c += __shfl_down(c, off);
    if ((t & 63) == 0) atomicAdd(&red[bit], c);
    __syncthreads();
    if (red[bit] >= KSEL) prefix = cand;
  }
  {
    int cg = 0;
    #pragma unroll
    for (int u = 0; u < 8; ++u)
      cg += (__float_as_uint(mine[u]) > prefix) ? 1 : 0;
    #pragma unroll
    for (int off = 32; off > 0; off >>= 1) cg += __shfl_down(cg, off);
    if ((t & 63) == 0) atomicAdd(&red[32], cg);
  }
  __syncthreads();
  const int need = KSEL - red[32];   // ties taken lowest-index-first (jax top_k)

  const int lo = g*BMq + BMq/2 - 153;   // ws=int(0.15*2048)=307, ws//2=153
  const int hi = g*BMq + BMq/2 + 153;
  const int ssum = ((hi < Nn) ? hi : Nn) - ((lo > 0) ? lo : 0);
  const bool vqg = (ssum + KSEL) < Nn;  // always true at this config

  #pragma unroll
  for (int u = 0; u < 8; ++u){
    int j = (u < 4) ? (ja + u) : (jb2 + u - 4);
    unsigned int bu = __float_as_uint(mine[u]);
    bool topk = bu > prefix;
    if (!topk && bu == prefix){
      int tr = 0;
      for (int jj = 0; jj < j; ++jj)
        tr += (__float_as_uint(bsv[jj]) == prefix) ? 1 : 0;
      topk = (tr < need);
    }
    bool rnd = jax_rand01((unsigned)(bid*Nn + j), k1a, k1b, k2a, k2b);
    bool st  = (j >= lo) && (j < hi);
    bool selb = st || ((rnd || topk) && vqg);
    if (selb){
      int slot = atomicAdd(&csel, 1);
      g_sel[(size_t)bid*Nn + slot] = (unsigned short)j;
    }
  }
  __syncthreads();
  if (t == 0) g_cnt[bid] = csel;
}

// ---------------- Kernel 3: one-pass attention, XCD-swizzled + register-prefetched ----------------
// Swizzle: each XCD (bid%8) owns 96 consecutive work items = 1.5 heads (3MB K/V < 4MB L2).
// Prefetch: V_c issued before QK_c; K_{c+1} issued before PV_c (safe now — reuse is structural).
__global__ __launch_bounds__(256) void k3_attn(const float* __restrict__ Q,
                                               const float* __restrict__ K,
                                               const float* __restrict__ V,
                                               const float* __restrict__ OC,
                                               float* __restrict__ out){
  const int bid0 = blockIdx.x;
  const int w    = (bid0 & 7)*96 + (bid0 >> 3);   // xcd-grouped work index
  const int half = w & 1;
  const int gg   = w >> 1;             // h*QGg + g
  const int h = gg / QGg, g = gg % QGg;
  const int t = threadIdx.x;
  __shared__ float q_s[32][Dd+4];
  __shared__ float kv_s[CK][Dd+4];
  __shared__ float s_s[32][CK+1];
  __shared__ float l_s[32];
  const int c = g_cnt[gg];
  const unsigned short* sel = g_sel + (size_t)gg*Nn;

  const float* qb = Q + ((size_t)h*Nn + (size_t)g*BMq + half*32)*Dd;
  #pragma unroll
  for (int it = 0; it < 4; ++it){
    int e = it*256 + t;                 // 1024 float4s = 32 rows x 32 f4
    int row = e >> 5, c4 = e & 31;
    float4 vq = ((const float4*)qb)[e];
    float4 sv; sv.x = vq.x*SCALE; sv.y = vq.y*SCALE; sv.z = vq.z*SCALE; sv.w = vq.w*SCALE;
    *(float4*)&q_s[row][c4*4] = sv;
  }
  if (t < 32) l_s[t] = 0.0f;

  const int rt = t & 15, kcol = (t >> 4)*2;
  const int d0 = (t >> 4)*8;           // PV column group
  float acc2[2][8] = {};
  float4 kreg[4], vreg[4];

  // prefetch K chunk 0
  #pragma unroll
  for (int it = 0; it < 4; ++it){
    int e = it*256 + t, row = e >> 5, c4 = e & 31;
    int j = (row < c) ? (int)sel[row] : 0;
    kreg[it] = ((const float4*)(K + ((size_t)h*Nn + j)*Dd))[c4];
  }
  #pragma unroll
  for (int it = 0; it < 4; ++it){
    int e = it*256 + t, row = e >> 5, c4 = e & 31;
    *(float4*)&kv_s[row][c4*4] = kreg[it];
  }
  __syncthreads();

  for (int c0 = 0; c0 < c; c0 += CK){
    const int cc = ((c - c0) < CK) ? (c - c0) : CK;
    // issue V chunk c0 loads (consumed after QK)
    #pragma unroll
    for (int it = 0; it < 4; ++it){
      int e = it*256 + t, row = e >> 5, c4 = e & 31;
      int idx = c0 + row;
      int j = (idx < c) ? (int)sel[idx] : 0;
      vreg[it] = ((const float4*)(V + ((size_t)h*Nn + j)*Dd))[c4];
    }
    // QK on kv_s (K chunk c0): rows {rt, rt+16} x cols {kcol, kcol+1}
    float a00=0.f, a01=0.f, a10=0.f, a11=0.f;
    #pragma unroll 8
    for (int d = 0; d < Dd; d += 4){
      float4 k0 = *(const float4*)&kv_s[kcol][d];
      float4 k1 = *(const float4*)&kv_s[kcol+1][d];
      float4 q0 = *(const float4*)&q_s[rt][d];
      float4 q1 = *(const float4*)&q_s[rt+16][d];
      a00 += q0.x*k0.x + q0.y*k0.y + q0.z*k0.z + q0.w*k0.w;
      a01 += q0.x*k1.x + q0.y*k1.y + q0.z*k1.z + q0.w*k1.w;
      a10 += q1.x*k0.x + q1.y*k0.y + q1.z*k0.z + q1.w*k0.w;
      a11 += q1.x*k1.x + q1.y*k1.y + q1.z*k1.z + q1.w*k1.w;
    }
    s_s[rt   ][kcol  ] = (kcol   < cc) ? __expf(a00) : 0.f;
    s_s[rt   ][kcol+1] = (kcol+1 < cc) ? __expf(a01) : 0.f;
    s_s[rt+16][kcol  ] = (kcol   < cc) ? __expf(a10) : 0.f;
    s_s[rt+16][kcol+1] = (kcol+1 < cc) ? __expf(a11) : 0.f;
    __syncthreads();
    // write V chunk into kv_s (vmcnt wait lands here, after QK compute)
    #pragma unroll
    for (int it = 0; it < 4; ++it){
      int e = it*256 + t, row = e >> 5, c4 = e & 31;
      *(float4*)&kv_s[row][c4*4] = vreg[it];
    }
    // row-sum accumulate (l)
    if (t < 32){
      float s = 0.f;
      #pragma unroll
      for (int c2 = 0; c2 < CK; ++c2) s += s_s[t][c2];
      l_s[t] += s;
    }
    __syncthreads();
    // issue K chunk c0+CK loads (consumed after PV)
    #pragma unroll
    for (int it = 0; it < 4; ++it){
      int e = it*256 + t, row = e >> 5, c4 = e & 31;
      int idx = c0 + CK + row;
      int j = (idx < c) ? (int)sel[idx] : 0;
      kreg[it] = ((const float4*)(K + ((size_t)h*Nn + j)*Dd))[c4];
    }
    // PV: rows {rt, rt+16}, cols d0..d0+7
    for (int c2 = 0; c2 < cc; ++c2){
      float p0 = s_s[rt][c2], p1 = s_s[rt+16][c2];
      float4 va = *(const float4*)&kv_s[c2][d0];
      float4 vb = *(const float4*)&kv_s[c2][d0+4];
      acc2[0][0] += p0*va.x; acc2[0][1] += p0*va.y;
      acc2[0][2] += p0*va.z; acc2[0][3] += p0*va.w;
      acc2[0][4] += p0*vb.x; acc2[0][5] += p0*vb.y;
      acc2[0][6] += p0*vb.z; acc2[0][7] += p0*vb.w;
      acc2[1][0] += p1*va.x; acc2[1][1] += p1*va.y;
      acc2[1][2] += p1*va.z; acc2[1][3] += p1*va.w;
      acc2[1][4] += p1*vb.x; acc2[1][5] += p1*vb.y;
      acc2[1][6] += p1*vb.z; acc2[1][7] += p1*vb.w;
    }
    __syncthreads();
    // write next K chunk into kv_s
    #pragma unroll
    for (int it = 0; it < 4; ++it){
      int e = it*256 + t, row = e >> 5, c4 = e & 31;
      *(float4*)&kv_s[row][c4*4] = kreg[it];
    }
    __syncthreads();
  }

  if (t < 32) l_s[t] = 1.0f / l_s[t];
  __syncthreads();

  #pragma unroll
  for (int rr = 0; rr < 2; ++rr){
    const int r = rr*16 + rt;
    const float il = l_s[r];
    size_t o = ((size_t)h*Nn + (size_t)g*BMq + half*32 + r)*Dd + d0;
    float4 ca = *(const float4*)(OC + o);
    float4 cb = *(const float4*)(OC + o + 4);
    float4 ra, rb;
    ra.x = acc2[rr][0]*il + ca.x; ra.y = acc2[rr][1]*il + ca.y;
    ra.z = acc2[rr][2]*il + ca.z; ra.w = acc2[rr][3]*il + ca.w;
    rb.x = acc2[rr][4]*il + cb.x; rb.y = acc2[rr][5]*il + cb.y;
    rb.z = acc2[rr][6]*il + cb.z; rb.w = acc2[rr][7]*il + cb.w;
    *(float4*)(out + o)     = ra;
    *(float4*)(out + o + 4) = rb;
  }
}

extern "C" void kernel_launch(void* const* d_in, const int* in_sizes, int n_in,
                              void* d_out, int out_size, void* d_ws, size_t ws_size,
                              hipStream_t stream) {
  (void)in_sizes; (void)n_in; (void)out_size; (void)d_ws; (void)ws_size;
  const float* Q  = (const float*)d_in[0];
  const float* K  = (const float*)d_in[1];
  const float* V  = (const float*)d_in[2];
  const float* OC = (const float*)d_in[3];
  float* out = (float*)d_out;
  hipLaunchKernelGGL(k1a_scores, dim3(Hh*16*16), dim3(256), 0, stream, Q, K);
  hipLaunchKernelGGL(k2_mask,    dim3(Hh*QGg),   dim3(256), 0, stream);
  hipLaunchKernelGGL(k3_attn,    dim3(Hh*QGg*2), dim3(256), 0, stream, Q, K, V, OC, out);
}

// Round 14
// 540.030 us; speedup vs baseline: 1.1869x; 1.1067x over previous
//
#include <hip/hip_runtime.h>
#include <math.h>

// SparseDiffAttn: B=1,H=12,N=2048,D=128, BM=64, top-k=192, static window [c-153,c+153),
// random keys via modern-JAX randint under jax_threefry_partitionable=True:
//   k1 = tf((0,1),(0,0)), k2 = tf((0,1),(0,1))        [fold-like split]
//   bits(k,i) = b1^b2 with (b1,b2) = tf(k,(0,i))      [partitionable random_bits]
//   offset = ((hi%100)*96 + lo%100) % 100; rnd <=> offset==0
// PRECISION: selection robust to ~1e-6 rel (fp32==fp64 masks) but NOT fp16-E (R10 failed).
// RULES LEARNED: (a) no register prefetch in k3 — R8 and R13 both show it destroys L2
// reuse (FETCH 28->87MB) even with XCD swizzle; barrier lockstep IS the reuse mechanism.
// (b) E materialization beats 2x QK recompute (R12). (c) k3 XCD swizzle: FETCH 157->28MB.
// THIS ROUND: E stored TILE-BLOCKED [h][gp][jb][128][128] so k2 streams contiguous 32KB
// slabs instead of 8KB-strided row walks (theory: TCC channel imbalance pins k2 at 1.5TB/s).
constexpr int Hh   = 12;
constexpr int Nn   = 2048;
constexpr int Dd   = 128;
constexpr int BMq  = 64;
constexpr int QGg  = 32;            // Nn/BMq
constexpr int KSEL = 192;           // 64 * round(0.1*2048/64)
constexpr int CK   = 32;            // key chunk (k3)
constexpr int DC   = 32;            // d-chunk (k1a)
constexpr int LSTR = 132;           // padded LDS row stride (floats), 16B-aligned
constexpr float SCALE = 0.08838834764831845f;  // 1/sqrt(128)

// persistent scratch (fully rewritten every launch before any read)
// g_E tile-blocked: tile (h,gp,jb) = 128x128 floats contiguous, row-major inside.
__device__ float          g_E [(size_t)Hh*16*16*128*128];   // 201 MB
__device__ float          g_lp[(size_t)Hh*Nn*16];           // per-jb partial row sums
__device__ unsigned short g_sel[Hh*QGg*Nn];
__device__ int            g_cnt[Hh*QGg];

__device__ __forceinline__ unsigned int rotl32(unsigned int x, int n){
  return (x << n) | (x >> (32 - n));
}

// threefry2x32, 20 rounds, arbitrary key
__device__ __forceinline__ void tf2x32(unsigned int k0, unsigned int k1,
                                       unsigned int x0, unsigned int x1,
                                       unsigned int &o0, unsigned int &o1){
  const unsigned int ks2 = 0x1BD11BDAu ^ k0 ^ k1;
  x0 += k0; x1 += k1;
  x0 += x1; x1 = rotl32(x1,13); x1 ^= x0;
  x0 += x1; x1 = rotl32(x1,15); x1 ^= x0;
  x0 += x1; x1 = rotl32(x1,26); x1 ^= x0;
  x0 += x1; x1 = rotl32(x1, 6); x1 ^= x0;
  x0 += k1; x1 += ks2 + 1u;
  x0 += x1; x1 = rotl32(x1,17); x1 ^= x0;
  x0 += x1; x1 = rotl32(x1,29); x1 ^= x0;
  x0 += x1; x1 = rotl32(x1,16); x1 ^= x0;
  x0 += x1; x1 = rotl32(x1,24); x1 ^= x0;
  x0 += ks2; x1 += k0 + 2u;
  x0 += x1; x1 = rotl32(x1,13); x1 ^= x0;
  x0 += x1; x1 = rotl32(x1,15); x1 ^= x0;
  x0 += x1; x1 = rotl32(x1,26); x1 ^= x0;
  x0 += x1; x1 = rotl32(x1, 6); x1 ^= x0;
  x0 += k0; x1 += k1 + 3u;
  x0 += x1; x1 = rotl32(x1,17); x1 ^= x0;
  x0 += x1; x1 = rotl32(x1,29); x1 ^= x0;
  x0 += x1; x1 = rotl32(x1,16); x1 ^= x0;
  x0 += x1; x1 = rotl32(x1,24); x1 ^= x0;
  x0 += k1; x1 += ks2 + 4u;
  x0 += x1; x1 = rotl32(x1,13); x1 ^= x0;
  x0 += x1; x1 = rotl32(x1,15); x1 ^= x0;
  x0 += x1; x1 = rotl32(x1,26); x1 ^= x0;
  x0 += x1; x1 = rotl32(x1, 6); x1 ^= x0;
  x0 += ks2; x1 += k0 + 5u;
  o0 = x0; o1 = x1;
}

// partitionable-threefry randint(key(1), ..., 0, 100) == 0 for flat element idx
__device__ __forceinline__ bool jax_rand01(unsigned int idx,
                                           unsigned int k1a, unsigned int k1b,
                                           unsigned int k2a, unsigned int k2b){
  unsigned int h0, h1, l0, l1;
  tf2x32(k1a, k1b, 0u, idx, h0, h1);
  tf2x32(k2a, k2b, 0u, idx, l0, l1);
  unsigned int h = h0 ^ h1;
  unsigned int l = l0 ^ l1;
  unsigned int off = ((h % 100u) * 96u + (l % 100u)) % 100u;
  return off == 0u;
}

// ---------------- Kernel 1a: one-pass E=__expf(QK^T*scale) (tile-blocked) + row sums ----------------
__global__ __launch_bounds__(256) void k1a_scores(const float* __restrict__ Q,
                                                  const float* __restrict__ K){
  const int bid = blockIdx.x;
  const int jb = bid & 15, gp = (bid >> 4) & 15, h = bid >> 8;
  const int t = threadIdx.x, tx = t & 15, ty = t >> 4;
  __shared__ float Qt[DC][LSTR];   // transposed, pre-scaled
  __shared__ float Kt[DC][LSTR];   // transposed
  __shared__ float lsum[128][17];

  const int R0 = gp*128, J0 = jb*128;
  const float* Qb = Q + ((size_t)h*Nn + R0)*Dd;
  const float* Kb = K + ((size_t)h*Nn + J0)*Dd;

  float acc[8][8] = {};
  float4 qreg[4], kreg[4];
  #pragma unroll
  for (int it = 0; it < 4; ++it){
    int e = it*256 + t, r = e >> 3, d4 = e & 7;
    qreg[it] = ((const float4*)(Qb + (size_t)r*Dd))[d4];
    kreg[it] = ((const float4*)(Kb + (size_t)r*Dd))[d4];
  }
  for (int c = 0; c < Dd/DC; ++c){
    #pragma unroll
    for (int it = 0; it < 4; ++it){
      int e = it*256 + t, r = e >> 3, d4 = e & 7;
      float4 qv = qreg[it], kv = kreg[it];
      Qt[d4*4+0][r] = qv.x*SCALE; Qt[d4*4+1][r] = qv.y*SCALE;
      Qt[d4*4+2][r] = qv.z*SCALE; Qt[d4*4+3][r] = qv.w*SCALE;
      Kt[d4*4+0][r] = kv.x; Kt[d4*4+1][r] = kv.y;
      Kt[d4*4+2][r] = kv.z; Kt[d4*4+3][r] = kv.w;
    }
    __syncthreads();
    if (c < Dd/DC - 1){
      const int d0 = (c+1)*DC;
      #pragma unroll
      for (int it = 0; it < 4; ++it){
        int e = it*256 + t, r = e >> 3, d4 = e & 7;
        qreg[it] = ((const float4*)(Qb + (size_t)r*Dd + d0))[d4];
        kreg[it] = ((const float4*)(Kb + (size_t)r*Dd + d0))[d4];
      }
    }
    #pragma unroll 8
    for (int dd = 0; dd < DC; ++dd){
      float a[8], b[8];
      *(float4*)&a[0] = *(const float4*)&Qt[dd][ty*8];
      *(float4*)&a[4] = *(const float4*)&Qt[dd][ty*8+4];
      *(float4*)&b[0] = *(const float4*)&Kt[dd][tx*8];
      *(float4*)&b[4] = *(const float4*)&Kt[dd][tx*8+4];
      #pragma unroll
      for (int i = 0; i < 8; ++i)
        #pragma unroll
        for (int j = 0; j < 8; ++j)
          acc[i][j] += a[i]*b[j];
    }
    __syncthreads();
  }

  float* tbase = &g_E[(((size_t)h*16 + gp)*16 + jb) * (128*128)];
  #pragma unroll
  for (int i = 0; i < 8; ++i){
    const int r = ty*8 + i;
    float ev[8]; float s = 0.f;
    #pragma unroll
    for (int j = 0; j < 8; ++j){ ev[j] = __expf(acc[i][j]); s += ev[j]; }
    lsum[r][tx] = s;
    float4 e0, e1;
    e0.x=ev[0]; e0.y=ev[1]; e0.z=ev[2]; e0.w=ev[3];
    e1.x=ev[4]; e1.y=ev[5]; e1.z=ev[6]; e1.w=ev[7];
    float* Ep = tbase + (size_t)r*128 + tx*8;
    *(float4*)Ep = e0;
    *(float4*)(Ep+4) = e1;
  }
  __syncthreads();
  if (t < 128){
    float s = 0.f;
    #pragma unroll
    for (int x = 0; x < 16; ++x) s += lsum[t][x];
    g_lp[((size_t)h*Nn + R0 + t)*16 + jb] = s;
  }
}

// ---------------- Kernel 2: slab-streaming bs colsum + top-k + random + static -> key list --------
// Block (h,g): streams 16 contiguous 32KB slabs (rows g*64..+63 of each jb tile).
__global__ __launch_bounds__(256) void k2_mask(){
  const int bid = blockIdx.x, h = bid / QGg, g = bid % QGg, t = threadIdx.x;
  __shared__ float bsv[Nn];          // 8 KB
  __shared__ float part[4][Nn];      // 32 KB: per-wave column partials
  __shared__ float il_s[BMq];
  __shared__ int red[33];
  __shared__ int csel;
  if (t < BMq){
    const float* lp = &g_lp[((size_t)h*Nn + g*BMq + t)*16];
    float s = 0.f;
    #pragma unroll
    for (int x = 0; x < 16; ++x) s += lp[x];
    il_s[t] = 1.0f / s;
  }
  if (t < 33) red[t] = 0;
  if (t == 0) csel = 0;
  __syncthreads();

  const int w = t >> 6, l = t & 63;
  const int rp = l >> 5;            // row within pair
  const int c4 = (l & 31) * 4;      // col within tile (float4)
  const size_t tb0 = ((size_t)h*16 + (g >> 1))*16;   // tile base index for this gp
  const size_t roff = (size_t)((g & 1)*64) * 128;

  float acc[16][4] = {};
  #pragma unroll
  for (int jb = 0; jb < 16; ++jb){
    const float* slab = g_E + (tb0 + jb)*(128*128) + roff;
    for (int p = w; p < 32; p += 4){      // 32 row-pairs, 8 per wave
      const int r = p*2 + rp;
      const float ilr = il_s[r];
      float4 e = *(const float4*)&slab[(size_t)r*128 + c4];
      acc[jb][0] += e.x*ilr; acc[jb][1] += e.y*ilr;
      acc[jb][2] += e.z*ilr; acc[jb][3] += e.w*ilr;
    }
  }
  // fold the two row-parity halves of each wave (lane l += lane l+32)
  #pragma unroll
  for (int jb = 0; jb < 16; ++jb)
    #pragma unroll
    for (int c = 0; c < 4; ++c)
      acc[jb][c] += __shfl_down(acc[jb][c], 32);
  if (l < 32){
    #pragma unroll
    for (int jb = 0; jb < 16; ++jb)
      *(float4*)&part[w][jb*128 + c4] = *(float4*)&acc[jb][0];
  }
  __syncthreads();

  // bs for this thread's 8 columns: j in {t*4..+3} u {1024+t*4..+3}
  const int ja = t*4, jb2 = 1024 + t*4;
  float4 s0, s1;
  {
    float4 a0 = *(float4*)&part[0][ja], a1 = *(float4*)&part[1][ja];
    float4 a2 = *(float4*)&part[2][ja], a3 = *(float4*)&part[3][ja];
    s0.x = a0.x+a1.x+a2.x+a3.x; s0.y = a0.y+a1.y+a2.y+a3.y;
    s0.z = a0.z+a1.z+a2.z+a3.z; s0.w = a0.w+a1.w+a2.w+a3.w;
    float4 b0 = *(float4*)&part[0][jb2], b1 = *(float4*)&part[1][jb2];
    float4 b2 = *(float4*)&part[2][jb2], b3 = *(float4*)&part[3][jb2];
    s1.x = b0.x+b1.x+b2.x+b3.x; s1.y = b0.y+b1.y+b2.y+b3.y;
    s1.z = b0.z+b1.z+b2.z+b3.z; s1.w = b0.w+b1.w+b2.w+b3.w;
  }
  *(float4*)&bsv[ja]  = s0;
  *(float4*)&bsv[jb2] = s1;
  float mine[8] = {s0.x,s0.y,s0.z,s0.w, s1.x,s1.y,s1.z,s1.w};
  __syncthreads();

  unsigned int k1a, k1b, k2a, k2b;
  tf2x32(0u, 1u, 0u, 0u, k1a, k1b);
  tf2x32(0u, 1u, 0u, 1u, k2a, k2b);

  // 192nd-largest via bitwise binary search on register values (positive -> uint order)
  unsigned int prefix = 0u;
  for (int bit = 31; bit >= 0; --bit){
    unsigned int cand = prefix | (1u << bit);
    int c = 0;
    #pragma unroll
    for (int u = 0; u < 8; ++u)
      c += (__float_as_uint(mine[u]) >= cand) ? 1 : 0;
    #pragma unroll
    for (int off = 32; off > 0; off >>= 1) c += __shfl_down(c, off);
    if ((t & 63) == 0) atomicAdd(&red[bit], c);
    __syncthreads();
    if (red[bit] >= KSEL) prefix = cand;
  }
  {
    int cg = 0;
    #pragma unroll
    for (int u = 0; u < 8; ++u)
      cg += (__float_as_uint(mine[u]) > prefix) ? 1 : 0;
    #pragma unroll
    for (int off = 32; off > 0; off >>= 1) cg += __shfl_down(cg, off);
    if ((t & 63) == 0) atomicAdd(&red[32], cg);
  }
  __syncthreads();
  const int need = KSEL - red[32];   // ties taken lowest-index-first (jax top_k)

  const int lo = g*BMq + BMq/2 - 153;   // ws=int(0.15*2048)=307, ws//2=153
  const int hi = g*BMq + BMq/2 + 153;
  const int ssum = ((hi < Nn) ? hi : Nn) - ((lo > 0) ? lo : 0);
  const bool vqg = (ssum + KSEL) < Nn;  // always true at this config

  #pragma unroll
  for (int u = 0; u < 8; ++u){
    int j = (u < 4) ? (ja + u) : (jb2 + u - 4);
    unsigned int bu = __float_as_uint(mine[u]);
    bool topk = bu > prefix;
    if (!topk && bu == prefix){
      int tr = 0;
      for (int jj = 0; jj < j; ++jj)
        tr += (__float_as_uint(bsv[jj]) == prefix) ? 1 : 0;
      topk = (tr < need);
    }
    bool rnd = jax_rand01((unsigned)(bid*Nn + j), k1a, k1b, k2a, k2b);
    bool st  = (j >= lo) && (j < hi);
    bool selb = st || ((rnd || topk) && vqg);
    if (selb){
      int slot = atomicAdd(&csel, 1);
      g_sel[(size_t)bid*Nn + slot] = (unsigned short)j;
    }
  }
  __syncthreads();
  if (t == 0) g_cnt[bid] = csel;
}

// ---------------- Kernel 3: one-pass attention, XCD-swizzled, NO prefetch (R12 form) --------------
__global__ __launch_bounds__(256) void k3_attn(const float* __restrict__ Q,
                                               const float* __restrict__ K,
                                               const float* __restrict__ V,
                                               const float* __restrict__ OC,
                                               float* __restrict__ out){
  const int bid0 = blockIdx.x;
  const int w    = (bid0 & 7)*96 + (bid0 >> 3);   // xcd-grouped work index
  const int half = w & 1;
  const int gg   = w >> 1;             // h*QGg + g
  const int h = gg / QGg, g = gg % QGg;
  const int t = threadIdx.x;
  __shared__ float q_s[32][Dd+4];
  __shared__ float kv_s[CK][Dd+4];
  __shared__ float s_s[32][CK+1];
  __shared__ float l_s[32];
  const int c = g_cnt[gg];
  const unsigned short* sel = g_sel + (size_t)gg*Nn;

  const float* qb = Q + ((size_t)h*Nn + (size_t)g*BMq + half*32)*Dd;
  #pragma unroll
  for (int it = 0; it < 4; ++it){
    int e = it*256 + t;                 // 1024 float4s = 32 rows x 32 f4
    int row = e >> 5, c4 = e & 31;
    float4 vq = ((const float4*)qb)[e];
    float4 sv; sv.x = vq.x*SCALE; sv.y = vq.y*SCALE; sv.z = vq.z*SCALE; sv.w = vq.w*SCALE;
    *(float4*)&q_s[row][c4*4] = sv;
  }
  if (t < 32) l_s[t] = 0.0f;
  __syncthreads();

  const int rt = t & 15, kcol = (t >> 4)*2;
  const int d0 = (t >> 4)*8;           // PV column group
  float acc2[2][8] = {};

  for (int c0 = 0; c0 < c; c0 += CK){
    const int cc = ((c - c0) < CK) ? (c - c0) : CK;
    // gather K chunk
    #pragma unroll
    for (int it = 0; it < 4; ++it){
      int e = it*256 + t, row = e >> 5, c4 = e & 31;
      int j = (row < cc) ? (int)sel[c0 + row] : 0;
      *(float4*)&kv_s[row][c4*4] = ((const float4*)(K + ((size_t)h*Nn + j)*Dd))[c4];
    }
    __syncthreads();
    float a00=0.f, a01=0.f, a10=0.f, a11=0.f;
    #pragma unroll 8
    for (int d = 0; d < Dd; d += 4){
      float4 k0 = *(const float4*)&kv_s[kcol][d];
      float4 k1 = *(const float4*)&kv_s[kcol+1][d];
      float4 q0 = *(const float4*)&q_s[rt][d];
      float4 q1 = *(const float4*)&q_s[rt+16][d];
      a00 += q0.x*k0.x + q0.y*k0.y + q0.z*k0.z + q0.w*k0.w;
      a01 += q0.x*k1.x + q0.y*k1.y + q0.z*k1.z + q0.w*k1.w;
      a10 += q1.x*k0.x + q1.y*k0.y + q1.z*k0.z + q1.w*k0.w;
      a11 += q1.x*k1.x + q1.y*k1.y + q1.z*k1.z + q1.w*k1.w;
    }
    s_s[rt   ][kcol  ] = (kcol   < cc) ? __expf(a00) : 0.f;
    s_s[rt   ][kcol+1] = (kcol+1 < cc) ? __expf(a01) : 0.f;
    s_s[rt+16][kcol  ] = (kcol   < cc) ? __expf(a10) : 0.f;
    s_s[rt+16][kcol+1] = (kcol+1 < cc) ? __expf(a11) : 0.f;
    __syncthreads();
    if (t < 32){
      float s = 0.f;
      #pragma unroll
      for (int c2 = 0; c2 < CK; ++c2) s += s_s[t][c2];
      l_s[t] += s;
    }
    // gather V chunk (overwrites kv_s; QK readers already past barrier)
    #pragma unroll
    for (int it = 0; it < 4; ++it){
      int e = it*256 + t, row = e >> 5, c4 = e & 31;
      int j = (row < cc) ? (int)sel[c0 + row] : 0;
      *(float4*)&kv_s[row][c4*4] = ((const float4*)(V + ((size_t)h*Nn + j)*Dd))[c4];
    }
    __syncthreads();
    for (int c2 = 0; c2 < cc; ++c2){
      float p0 = s_s[rt][c2], p1 = s_s[rt+16][c2];
      float4 va = *(const float4*)&kv_s[c2][d0];
      float4 vb = *(const float4*)&kv_s[c2][d0+4];
      acc2[0][0] += p0*va.x; acc2[0][1] += p0*va.y;
      acc2[0][2] += p0*va.z; acc2[0][3] += p0*va.w;
      acc2[0][4] += p0*vb.x; acc2[0][5] += p0*vb.y;
      acc2[0][6] += p0*vb.z; acc2[0][7] += p0*vb.w;
      acc2[1][0] += p1*va.x; acc2[1][1] += p1*va.y;
      acc2[1][2] += p1*va.z; acc2[1][3] += p1*va.w;
      acc2[1][4] += p1*vb.x; acc2[1][5] += p1*vb.y;
      acc2[1][6] += p1*vb.z; acc2[1][7] += p1*vb.w;
    }
    __syncthreads();
  }

  if (t < 32) l_s[t] = 1.0f / l_s[t];
  __syncthreads();

  #pragma unroll
  for (int rr = 0; rr < 2; ++rr){
    const int r = rr*16 + rt;
    const float il = l_s[r];
    size_t o = ((size_t)h*Nn + (size_t)g*BMq + half*32 + r)*Dd + d0;
    float4 ca = *(const float4*)(OC + o);
    float4 cb = *(const float4*)(OC + o + 4);
    float4 ra, rb;
    ra.x = acc2[rr][0]*il + ca.x; ra.y = acc2[rr][1]*il + ca.y;
    ra.z = acc2[rr][2]*il + ca.z; ra.w = acc2[rr][3]*il + ca.w;
    rb.x = acc2[rr][4]*il + cb.x; rb.y = acc2[rr][5]*il + cb.y;
    rb.z = acc2[rr][6]*il + cb.z; rb.w = acc2[rr][7]*il + cb.w;
    *(float4*)(out + o)     = ra;
    *(float4*)(out + o + 4) = rb;
  }
}

extern "C" void kernel_launch(void* const* d_in, const int* in_sizes, int n_in,
                              void* d_out, int out_size, void* d_ws, size_t ws_size,
                              hipStream_t stream) {
  (void)in_sizes; (void)n_in; (void)out_size; (void)d_ws; (void)ws_size;
  const float* Q  = (const float*)d_in[0];
  const float* K  = (const float*)d_in[1];
  const float* V  = (const float*)d_in[2];
  const float* OC = (const float*)d_in[3];
  float* out = (float*)d_out;
  hipLaunchKernelGGL(k1a_scores, dim3(Hh*16*16), dim3(256), 0, stream, Q, K);
  hipLaunchKernelGGL(k2_mask,    dim3(Hh*QGg),   dim3(256), 0, stream);
  hipLaunchKernelGGL(k3_attn,    dim3(Hh*QGg*2), dim3(256), 0, stream, Q, K, V, OC, out);
}

// Round 15
// 539.304 us; speedup vs baseline: 1.1885x; 1.0013x over previous
//
#include <hip/hip_runtime.h>
#include <math.h>

// SparseDiffAttn: B=1,H=12,N=2048,D=128, BM=64, top-k=192, static window [c-153,c+153),
// random keys via modern-JAX randint under jax_threefry_partitionable=True:
//   k1 = tf((0,1),(0,0)), k2 = tf((0,1),(0,1))        [fold-like split]
//   bits(k,i) = b1^b2 with (b1,b2) = tf(k,(0,i))      [partitionable random_bits]
//   offset = ((hi%100)*96 + lo%100) % 100; rnd <=> offset==0
// PRECISION: selection robust to ~1e-6 rel (fp32==fp64 masks) but NOT fp16-E (R10 failed).
// RULES LEARNED: (a) no register prefetch in k3 — R8/R13: destroys L2 reuse (FETCH 28->87MB)
// even with XCD swizzle; barrier lockstep IS the reuse mechanism. (b) E materialization beats
// 2x QK recompute (R12). (c) k3 XCD swizzle: FETCH 157->28MB. (d) k2's ~1.1TB/s plateau was
// layout-independent (R7/R9/R14) -> occupancy-bound, not channel-bound: fix = 6144-block split.
constexpr int Hh   = 12;
constexpr int Nn   = 2048;
constexpr int Dd   = 128;
constexpr int BMq  = 64;
constexpr int QGg  = 32;            // Nn/BMq
constexpr int KSEL = 192;           // 64 * round(0.1*2048/64)
constexpr int CK   = 32;            // key chunk (k3)
constexpr int DC   = 32;            // d-chunk (k1a)
constexpr int LSTR = 132;           // padded LDS row stride (floats), 16B-aligned
constexpr float SCALE = 0.08838834764831845f;  // 1/sqrt(128)

// persistent scratch (fully rewritten every launch before any read)
// g_E tile-blocked: tile (h,gp,jb) = 128x128 floats contiguous, row-major inside.
__device__ float          g_E [(size_t)Hh*16*16*128*128];   // 201 MB
__device__ float          g_lp[(size_t)Hh*Nn*16];           // per-jb partial row sums
__device__ float          g_bs[(size_t)Hh*QGg*Nn];          // colsum scores (3 MB)
__device__ unsigned short g_sel[Hh*QGg*Nn];
__device__ int            g_cnt[Hh*QGg];

__device__ __forceinline__ unsigned int rotl32(unsigned int x, int n){
  return (x << n) | (x >> (32 - n));
}

// threefry2x32, 20 rounds, arbitrary key
__device__ __forceinline__ void tf2x32(unsigned int k0, unsigned int k1,
                                       unsigned int x0, unsigned int x1,
                                       unsigned int &o0, unsigned int &o1){
  const unsigned int ks2 = 0x1BD11BDAu ^ k0 ^ k1;
  x0 += k0; x1 += k1;
  x0 += x1; x1 = rotl32(x1,13); x1 ^= x0;
  x0 += x1; x1 = rotl32(x1,15); x1 ^= x0;
  x0 += x1; x1 = rotl32(x1,26); x1 ^= x0;
  x0 += x1; x1 = rotl32(x1, 6); x1 ^= x0;
  x0 += k1; x1 += ks2 + 1u;
  x0 += x1; x1 = rotl32(x1,17); x1 ^= x0;
  x0 += x1; x1 = rotl32(x1,29); x1 ^= x0;
  x0 += x1; x1 = rotl32(x1,16); x1 ^= x0;
  x0 += x1; x1 = rotl32(x1,24); x1 ^= x0;
  x0 += ks2; x1 += k0 + 2u;
  x0 += x1; x1 = rotl32(x1,13); x1 ^= x0;
  x0 += x1; x1 = rotl32(x1,15); x1 ^= x0;
  x0 += x1; x1 = rotl32(x1,26); x1 ^= x0;
  x0 += x1; x1 = rotl32(x1, 6); x1 ^= x0;
  x0 += k0; x1 += k1 + 3u;
  x0 += x1; x1 = rotl32(x1,17); x1 ^= x0;
  x0 += x1; x1 = rotl32(x1,29); x1 ^= x0;
  x0 += x1; x1 = rotl32(x1,16); x1 ^= x0;
  x0 += x1; x1 = rotl32(x1,24); x1 ^= x0;
  x0 += k1; x1 += ks2 + 4u;
  x0 += x1; x1 = rotl32(x1,13); x1 ^= x0;
  x0 += x1; x1 = rotl32(x1,15); x1 ^= x0;
  x0 += x1; x1 = rotl32(x1,26); x1 ^= x0;
  x0 += x1; x1 = rotl32(x1, 6); x1 ^= x0;
  x0 += ks2; x1 += k0 + 5u;
  o0 = x0; o1 = x1;
}

// partitionable-threefry randint(key(1), ..., 0, 100) == 0 for flat element idx
__device__ __forceinline__ bool jax_rand01(unsigned int idx,
                                           unsigned int k1a, unsigned int k1b,
                                           unsigned int k2a, unsigned int k2b){
  unsigned int h0, h1, l0, l1;
  tf2x32(k1a, k1b, 0u, idx, h0, h1);
  tf2x32(k2a, k2b, 0u, idx, l0, l1);
  unsigned int h = h0 ^ h1;
  unsigned int l = l0 ^ l1;
  unsigned int off = ((h % 100u) * 96u + (l % 100u)) % 100u;
  return off == 0u;
}

// ---------------- Kernel 1a: one-pass E=__expf(QK^T*scale) (tile-blocked) + row sums ----------------
__global__ __launch_bounds__(256) void k1a_scores(const float* __restrict__ Q,
                                                  const float* __restrict__ K){
  const int bid = blockIdx.x;
  const int jb = bid & 15, gp = (bid >> 4) & 15, h = bid >> 8;
  const int t = threadIdx.x, tx = t & 15, ty = t >> 4;
  __shared__ float Qt[DC][LSTR];   // transposed, pre-scaled
  __shared__ float Kt[DC][LSTR];   // transposed
  __shared__ float lsum[128][17];

  const int R0 = gp*128, J0 = jb*128;
  const float* Qb = Q + ((size_t)h*Nn + R0)*Dd;
  const float* Kb = K + ((size_t)h*Nn + J0)*Dd;

  float acc[8][8] = {};
  float4 qreg[4], kreg[4];
  #pragma unroll
  for (int it = 0; it < 4; ++it){
    int e = it*256 + t, r = e >> 3, d4 = e & 7;
    qreg[it] = ((const float4*)(Qb + (size_t)r*Dd))[d4];
    kreg[it] = ((const float4*)(Kb + (size_t)r*Dd))[d4];
  }
  for (int c = 0; c < Dd/DC; ++c){
    #pragma unroll
    for (int it = 0; it < 4; ++it){
      int e = it*256 + t, r = e >> 3, d4 = e & 7;
      float4 qv = qreg[it], kv = kreg[it];
      Qt[d4*4+0][r] = qv.x*SCALE; Qt[d4*4+1][r] = qv.y*SCALE;
      Qt[d4*4+2][r] = qv.z*SCALE; Qt[d4*4+3][r] = qv.w*SCALE;
      Kt[d4*4+0][r] = kv.x; Kt[d4*4+1][r] = kv.y;
      Kt[d4*4+2][r] = kv.z; Kt[d4*4+3][r] = kv.w;
    }
    __syncthreads();
    if (c < Dd/DC - 1){
      const int d0 = (c+1)*DC;
      #pragma unroll
      for (int it = 0; it < 4; ++it){
        int e = it*256 + t, r = e >> 3, d4 = e & 7;
        qreg[it] = ((const float4*)(Qb + (size_t)r*Dd + d0))[d4];
        kreg[it] = ((const float4*)(Kb + (size_t)r*Dd + d0))[d4];
      }
    }
    #pragma unroll 8
    for (int dd = 0; dd < DC; ++dd){
      float a[8], b[8];
      *(float4*)&a[0] = *(const float4*)&Qt[dd][ty*8];
      *(float4*)&a[4] = *(const float4*)&Qt[dd][ty*8+4];
      *(float4*)&b[0] = *(const float4*)&Kt[dd][tx*8];
      *(float4*)&b[4] = *(const float4*)&Kt[dd][tx*8+4];
      #pragma unroll
      for (int i = 0; i < 8; ++i)
        #pragma unroll
        for (int j = 0; j < 8; ++j)
          acc[i][j] += a[i]*b[j];
    }
    __syncthreads();
  }

  float* tbase = &g_E[(((size_t)h*16 + gp)*16 + jb) * (128*128)];
  #pragma unroll
  for (int i = 0; i < 8; ++i){
    const int r = ty*8 + i;
    float ev[8]; float s = 0.f;
    #pragma unroll
    for (int j = 0; j < 8; ++j){ ev[j] = __expf(acc[i][j]); s += ev[j]; }
    lsum[r][tx] = s;
    float4 e0, e1;
    e0.x=ev[0]; e0.y=ev[1]; e0.z=ev[2]; e0.w=ev[3];
    e1.x=ev[4]; e1.y=ev[5]; e1.z=ev[6]; e1.w=ev[7];
    float* Ep = tbase + (size_t)r*128 + tx*8;
    *(float4*)Ep = e0;
    *(float4*)(Ep+4) = e1;
  }
  __syncthreads();
  if (t < 128){
    float s = 0.f;
    #pragma unroll
    for (int x = 0; x < 16; ++x) s += lsum[t][x];
    g_lp[((size_t)h*Nn + R0 + t)*16 + jb] = s;
  }
}

// ---------------- Kernel 2a: massively-parallel weighted colsum (6144 blocks) ----------------
// Block (h,g,jb): reads one contiguous 32KB slab (64 rows x 128 cols of a tile),
// writes 128 bs values. 24 blocks/CU — latency fully hidden.
__global__ __launch_bounds__(256) void k2a_colsum(){
  const int bid = blockIdx.x;            // h*512 + g*16 + jb
  const int jb = bid & 15;
  const int g  = (bid >> 4) & 31;
  const int h  = bid >> 9;
  const int t = threadIdx.x;
  __shared__ float il_s[BMq];
  __shared__ float part[8][132];
  if (t < BMq){
    const float* lp = &g_lp[((size_t)h*Nn + g*BMq + t)*16];
    float s = 0.f;
    #pragma unroll
    for (int x = 0; x < 16; ++x) s += lp[x];
    il_s[t] = 1.0f / s;
  }
  __syncthreads();
  const int c4 = t & 31, rg = t >> 5;    // 32 f4-cols x 8 row-groups
  const float* slab = g_E + (((size_t)h*16 + (g >> 1))*16 + jb)*(128*128)
                          + (size_t)((g & 1)*64)*128;
  float4 s = {0.f,0.f,0.f,0.f};
  #pragma unroll
  for (int rr = 0; rr < 8; ++rr){
    const int r = rg*8 + rr;
    const float w = il_s[r];
    float4 e = *(const float4*)&slab[(size_t)r*128 + c4*4];
    s.x += e.x*w; s.y += e.y*w; s.z += e.z*w; s.w += e.w*w;
  }
  *(float4*)&part[rg][c4*4] = s;
  __syncthreads();
  if (t < 32){
    float4 acc = {0.f,0.f,0.f,0.f};
    #pragma unroll
    for (int u = 0; u < 8; ++u){
      float4 p = *(float4*)&part[u][t*4];
      acc.x += p.x; acc.y += p.y; acc.z += p.z; acc.w += p.w;
    }
    *(float4*)&g_bs[((size_t)h*QGg + g)*Nn + jb*128 + t*4] = acc;
  }
}

// ---------------- Kernel 2b: top-k + random + static window -> compacted key list ----------------
__global__ __launch_bounds__(256) void k2b_mask(){
  const int bid = blockIdx.x, g = bid % QGg, t = threadIdx.x;
  __shared__ float bsv[Nn];
  __shared__ int red[33];
  __shared__ int csel;
  const float* src = g_bs + (size_t)bid*Nn;
  float mine[8];
  {
    float4 a = *(const float4*)&src[t*4];
    float4 b = *(const float4*)&src[1024 + t*4];
    *(float4*)&bsv[t*4] = a;
    *(float4*)&bsv[1024 + t*4] = b;
    mine[0]=a.x; mine[1]=a.y; mine[2]=a.z; mine[3]=a.w;
    mine[4]=b.x; mine[5]=b.y; mine[6]=b.z; mine[7]=b.w;
  }
  if (t < 33) red[t] = 0;
  if (t == 0) csel = 0;
  __syncthreads();

  unsigned int k1a, k1b, k2a, k2b;
  tf2x32(0u, 1u, 0u, 0u, k1a, k1b);
  tf2x32(0u, 1u, 0u, 1u, k2a, k2b);

  // 192nd-largest via bitwise binary search (positive -> uint order)
  unsigned int prefix = 0u;
  for (int bit = 31; bit >= 0; --bit){
    unsigned int cand = prefix | (1u << bit);
    int c = 0;
    #pragma unroll
    for (int u = 0; u < 8; ++u)
      c += (__float_as_uint(mine[u]) >= cand) ? 1 : 0;
    #pragma unroll
    for (int off = 32; off > 0; off >>= 1) c += __shfl_down(c, off);
    if ((t & 63) == 0) atomicAdd(&red[bit], c);
    __syncthreads();
    if (red[bit] >= KSEL) prefix = cand;
  }
  {
    int cg = 0;
    #pragma unroll
    for (int u = 0; u < 8; ++u)
      cg += (__float_as_uint(mine[u]) > prefix) ? 1 : 0;
    #pragma unroll
    for (int off = 32; off > 0; off >>= 1) cg += __shfl_down(cg, off);
    if ((t & 63) == 0) atomicAdd(&red[32], cg);
  }
  __syncthreads();
  const int need = KSEL - red[32];   // ties taken lowest-index-first (jax top_k)

  const int lo = g*BMq + BMq/2 - 153;   // ws=int(0.15*2048)=307, ws//2=153
  const int hi = g*BMq + BMq/2 + 153;
  const int ssum = ((hi < Nn) ? hi : Nn) - ((lo > 0) ? lo : 0);
  const bool vqg = (ssum + KSEL) < Nn;  // always true at this config

  #pragma unroll
  for (int u = 0; u < 8; ++u){
    int j = (u < 4) ? (t*4 + u) : (1024 + t*4 + u - 4);
    unsigned int bu = __float_as_uint(mine[u]);
    bool topk = bu > prefix;
    if (!topk && bu == prefix){
      int tr = 0;
      for (int jj = 0; jj < j; ++jj)
        tr += (__float_as_uint(bsv[jj]) == prefix) ? 1 : 0;
      topk = (tr < need);
    }
    bool rnd = jax_rand01((unsigned)(bid*Nn + j), k1a, k1b, k2a, k2b);
    bool st  = (j >= lo) && (j < hi);
    bool selb = st || ((rnd || topk) && vqg);
    if (selb){
      int slot = atomicAdd(&csel, 1);
      g_sel[(size_t)bid*Nn + slot] = (unsigned short)j;
    }
  }
  __syncthreads();
  if (t == 0) g_cnt[bid] = csel;
}

// ---------------- Kernel 3: one-pass attention, XCD-swizzled, NO prefetch ----------------
__global__ __launch_bounds__(256) void k3_attn(const float* __restrict__ Q,
                                               const float* __restrict__ K,
                                               const float* __restrict__ V,
                                               const float* __restrict__ OC,
                                               float* __restrict__ out){
  const int bid0 = blockIdx.x;
  const int w    = (bid0 & 7)*96 + (bid0 >> 3);   // xcd-grouped work index
  const int half = w & 1;
  const int gg   = w >> 1;             // h*QGg + g
  const int h = gg / QGg, g = gg % QGg;
  const int t = threadIdx.x;
  __shared__ float q_s[32][Dd+4];
  __shared__ float kv_s[CK][Dd+4];
  __shared__ float s_s[32][CK+1];
  __shared__ float l_s[32];
  const int c = g_cnt[gg];
  const unsigned short* sel = g_sel + (size_t)gg*Nn;

  const float* qb = Q + ((size_t)h*Nn + (size_t)g*BMq + half*32)*Dd;
  #pragma unroll
  for (int it = 0; it < 4; ++it){
    int e = it*256 + t;                 // 1024 float4s = 32 rows x 32 f4
    int row = e >> 5, c4 = e & 31;
    float4 vq = ((const float4*)qb)[e];
    float4 sv; sv.x = vq.x*SCALE; sv.y = vq.y*SCALE; sv.z = vq.z*SCALE; sv.w = vq.w*SCALE;
    *(float4*)&q_s[row][c4*4] = sv;
  }
  if (t < 32) l_s[t] = 0.0f;
  __syncthreads();

  const int rt = t & 15, kcol = (t >> 4)*2;
  const int d0 = (t >> 4)*8;           // PV column group
  float acc2[2][8] = {};

  for (int c0 = 0; c0 < c; c0 += CK){
    const int cc = ((c - c0) < CK) ? (c - c0) : CK;
    // gather K chunk
    #pragma unroll
    for (int it = 0; it < 4; ++it){
      int e = it*256 + t, row = e >> 5, c4 = e & 31;
      int j = (row < cc) ? (int)sel[c0 + row] : 0;
      *(float4*)&kv_s[row][c4*4] = ((const float4*)(K + ((size_t)h*Nn + j)*Dd))[c4];
    }
    __syncthreads();
    float a00=0.f, a01=0.f, a10=0.f, a11=0.f;
    #pragma unroll 8
    for (int d = 0; d < Dd; d += 4){
      float4 k0 = *(const float4*)&kv_s[kcol][d];
      float4 k1 = *(const float4*)&kv_s[kcol+1][d];
      float4 q0 = *(const float4*)&q_s[rt][d];
      float4 q1 = *(const float4*)&q_s[rt+16][d];
      a00 += q0.x*k0.x + q0.y*k0.y + q0.z*k0.z + q0.w*k0.w;
      a01 += q0.x*k1.x + q0.y*k1.y + q0.z*k1.z + q0.w*k1.w;
      a10 += q1.x*k0.x + q1.y*k0.y + q1.z*k0.z + q1.w*k0.w;
      a11 += q1.x*k1.x + q1.y*k1.y + q1.z*k1.z + q1.w*k1.w;
    }
    s_s[rt   ][kcol  ] = (kcol   < cc) ? __expf(a00) : 0.f;
    s_s[rt   ][kcol+1] = (kcol+1 < cc) ? __expf(a01) : 0.f;
    s_s[rt+16][kcol  ] = (kcol   < cc) ? __expf(a10) : 0.f;
    s_s[rt+16][kcol+1] = (kcol+1 < cc) ? __expf(a11) : 0.f;
    __syncthreads();
    if (t < 32){
      float s = 0.f;
      #pragma unroll
      for (int c2 = 0; c2 < CK; ++c2) s += s_s[t][c2];
      l_s[t] += s;
    }
    // gather V chunk (overwrites kv_s; QK readers already past barrier)
    #pragma unroll
    for (int it = 0; it < 4; ++it){
      int e = it*256 + t, row = e >> 5, c4 = e & 31;
      int j = (row < cc) ? (int)sel[c0 + row] : 0;
      *(float4*)&kv_s[row][c4*4] = ((const float4*)(V + ((size_t)h*Nn + j)*Dd))[c4];
    }
    __syncthreads();
    for (int c2 = 0; c2 < cc; ++c2){
      float p0 = s_s[rt][c2], p1 = s_s[rt+16][c2];
      float4 va = *(const float4*)&kv_s[c2][d0];
      float4 vb = *(const float4*)&kv_s[c2][d0+4];
      acc2[0][0] += p0*va.x; acc2[0][1] += p0*va.y;
      acc2[0][2] += p0*va.z; acc2[0][3] += p0*va.w;
      acc2[0][4] += p0*vb.x; acc2[0][5] += p0*vb.y;
      acc2[0][6] += p0*vb.z; acc2[0][7] += p0*vb.w;
      acc2[1][0] += p1*va.x; acc2[1][1] += p1*va.y;
      acc2[1][2] += p1*va.z; acc2[1][3] += p1*va.w;
      acc2[1][4] += p1*vb.x; acc2[1][5] += p1*vb.y;
      acc2[1][6] += p1*vb.z; acc2[1][7] += p1*vb.w;
    }
    __syncthreads();
  }

  if (t < 32) l_s[t] = 1.0f / l_s[t];
  __syncthreads();

  #pragma unroll
  for (int rr = 0; rr < 2; ++rr){
    const int r = rr*16 + rt;
    const float il = l_s[r];
    size_t o = ((size_t)h*Nn + (size_t)g*BMq + half*32 + r)*Dd + d0;
    float4 ca = *(const float4*)(OC + o);
    float4 cb = *(const float4*)(OC + o + 4);
    float4 ra, rb;
    ra.x = acc2[rr][0]*il + ca.x; ra.y = acc2[rr][1]*il + ca.y;
    ra.z = acc2[rr][2]*il + ca.z; ra.w = acc2[rr][3]*il + ca.w;
    rb.x = acc2[rr][4]*il + cb.x; rb.y = acc2[rr][5]*il + cb.y;
    rb.z = acc2[rr][6]*il + cb.z; rb.w = acc2[rr][7]*il + cb.w;
    *(float4*)(out + o)     = ra;
    *(float4*)(out + o + 4) = rb;
  }
}

extern "C" void kernel_launch(void* const* d_in, const int* in_sizes, int n_in,
                              void* d_out, int out_size, void* d_ws, size_t ws_size,
                              hipStream_t stream) {
  (void)in_sizes; (void)n_in; (void)out_size; (void)d_ws; (void)ws_size;
  const float* Q  = (const float*)d_in[0];
  const float* K  = (const float*)d_in[1];
  const float* V  = (const float*)d_in[2];
  const float* OC = (const float*)d_in[3];
  float* out = (float*)d_out;
  hipLaunchKernelGGL(k1a_scores, dim3(Hh*16*16),    dim3(256), 0, stream, Q, K);
  hipLaunchKernelGGL(k2a_colsum, dim3(Hh*QGg*16),   dim3(256), 0, stream);
  hipLaunchKernelGGL(k2b_mask,   dim3(Hh*QGg),      dim3(256), 0, stream);
  hipLaunchKernelGGL(k3_attn,    dim3(Hh*QGg*2),    dim3(256), 0, stream, Q, K, V, OC, out);
}

// Round 17
// 538.990 us; speedup vs baseline: 1.1891x; 1.0006x over previous
//
#include <hip/hip_runtime.h>
#include <math.h>

// SparseDiffAttn: B=1,H=12,N=2048,D=128, BM=64, top-k=192, static window [c-153,c+153),
// random keys via modern-JAX randint under jax_threefry_partitionable=True:
//   k1 = tf((0,1),(0,0)), k2 = tf((0,1),(0,1))        [fold-like split]
//   bits(k,i) = b1^b2 with (b1,b2) = tf(k,(0,i))      [partitionable random_bits]
//   offset = ((hi%100)*96 + lo%100) % 100; rnd <=> offset==0
// PRECISION: selection robust to ~1e-6 rel (fp32==fp64 masks) but NOT fp16-E (R10 failed).
// RULES LEARNED: (a) no register prefetch in k3 — R8/R13: destroys L2 reuse even with XCD
// swizzle; barrier lockstep IS the reuse mechanism. (b) E materialization beats 2x QK
// recompute (R12). (c) k3 XCD swizzle: FETCH 157->28MB. (d) k2's ~1.1TB/s E-read plateau is
// layout- AND occupancy-independent (R7/R9/R14/R15); k1a's E-write also ~1.2TB/s.
// THIS ROUND (R16 retry): E stream bypasses caches (nontemporal store/load via native
// ext_vector_type — HIP float4* is rejected by the builtin) to test the L2-thrash hypothesis.
constexpr int Hh   = 12;
constexpr int Nn   = 2048;
constexpr int Dd   = 128;
constexpr int BMq  = 64;
constexpr int QGg  = 32;            // Nn/BMq
constexpr int KSEL = 192;           // 64 * round(0.1*2048/64)
constexpr int CK   = 32;            // key chunk (k3)
constexpr int DC   = 32;            // d-chunk (k1a)
constexpr int LSTR = 132;           // padded LDS row stride (floats), 16B-aligned
constexpr float SCALE = 0.08838834764831845f;  // 1/sqrt(128)

typedef float vf4 __attribute__((ext_vector_type(4)));  // native vec for NT builtins

// persistent scratch (fully rewritten every launch before any read)
// g_E tile-blocked: tile (h,gp,jb) = 128x128 floats contiguous, row-major inside.
__device__ float          g_E [(size_t)Hh*16*16*128*128];   // 201 MB
__device__ float          g_lp[(size_t)Hh*Nn*16];           // per-jb partial row sums
__device__ float          g_bs[(size_t)Hh*QGg*Nn];          // colsum scores (3 MB)
__device__ unsigned short g_sel[Hh*QGg*Nn];
__device__ int            g_cnt[Hh*QGg];

__device__ __forceinline__ unsigned int rotl32(unsigned int x, int n){
  return (x << n) | (x >> (32 - n));
}

// threefry2x32, 20 rounds, arbitrary key
__device__ __forceinline__ void tf2x32(unsigned int k0, unsigned int k1,
                                       unsigned int x0, unsigned int x1,
                                       unsigned int &o0, unsigned int &o1){
  const unsigned int ks2 = 0x1BD11BDAu ^ k0 ^ k1;
  x0 += k0; x1 += k1;
  x0 += x1; x1 = rotl32(x1,13); x1 ^= x0;
  x0 += x1; x1 = rotl32(x1,15); x1 ^= x0;
  x0 += x1; x1 = rotl32(x1,26); x1 ^= x0;
  x0 += x1; x1 = rotl32(x1, 6); x1 ^= x0;
  x0 += k1; x1 += ks2 + 1u;
  x0 += x1; x1 = rotl32(x1,17); x1 ^= x0;
  x0 += x1; x1 = rotl32(x1,29); x1 ^= x0;
  x0 += x1; x1 = rotl32(x1,16); x1 ^= x0;
  x0 += x1; x1 = rotl32(x1,24); x1 ^= x0;
  x0 += ks2; x1 += k0 + 2u;
  x0 += x1; x1 = rotl32(x1,13); x1 ^= x0;
  x0 += x1; x1 = rotl32(x1,15); x1 ^= x0;
  x0 += x1; x1 = rotl32(x1,26); x1 ^= x0;
  x0 += x1; x1 = rotl32(x1, 6); x1 ^= x0;
  x0 += k0; x1 += k1 + 3u;
  x0 += x1; x1 = rotl32(x1,17); x1 ^= x0;
  x0 += x1; x1 = rotl32(x1,29); x1 ^= x0;
  x0 += x1; x1 = rotl32(x1,16); x1 ^= x0;
  x0 += x1; x1 = rotl32(x1,24); x1 ^= x0;
  x0 += k1; x1 += ks2 + 4u;
  x0 += x1; x1 = rotl32(x1,13); x1 ^= x0;
  x0 += x1; x1 = rotl32(x1,15); x1 ^= x0;
  x0 += x1; x1 = rotl32(x1,26); x1 ^= x0;
  x0 += x1; x1 = rotl32(x1, 6); x1 ^= x0;
  x0 += ks2; x1 += k0 + 5u;
  o0 = x0; o1 = x1;
}

// partitionable-threefry randint(key(1), ..., 0, 100) == 0 for flat element idx
__device__ __forceinline__ bool jax_rand01(unsigned int idx,
                                           unsigned int k1a, unsigned int k1b,
                                           unsigned int k2a, unsigned int k2b){
  unsigned int h0, h1, l0, l1;
  tf2x32(k1a, k1b, 0u, idx, h0, h1);
  tf2x32(k2a, k2b, 0u, idx, l0, l1);
  unsigned int h = h0 ^ h1;
  unsigned int l = l0 ^ l1;
  unsigned int off = ((h % 100u) * 96u + (l % 100u)) % 100u;
  return off == 0u;
}

// ---------------- Kernel 1a: one-pass E=__expf(QK^T*scale) (tile-blocked, NT stores) ----------------
__global__ __launch_bounds__(256) void k1a_scores(const float* __restrict__ Q,
                                                  const float* __restrict__ K){
  const int bid = blockIdx.x;
  const int jb = bid & 15, gp = (bid >> 4) & 15, h = bid >> 8;
  const int t = threadIdx.x, tx = t & 15, ty = t >> 4;
  __shared__ float Qt[DC][LSTR];   // transposed, pre-scaled
  __shared__ float Kt[DC][LSTR];   // transposed
  __shared__ float lsum[128][17];

  const int R0 = gp*128, J0 = jb*128;
  const float* Qb = Q + ((size_t)h*Nn + R0)*Dd;
  const float* Kb = K + ((size_t)h*Nn + J0)*Dd;

  float acc[8][8] = {};
  float4 qreg[4], kreg[4];
  #pragma unroll
  for (int it = 0; it < 4; ++it){
    int e = it*256 + t, r = e >> 3, d4 = e & 7;
    qreg[it] = ((const float4*)(Qb + (size_t)r*Dd))[d4];
    kreg[it] = ((const float4*)(Kb + (size_t)r*Dd))[d4];
  }
  for (int c = 0; c < Dd/DC; ++c){
    #pragma unroll
    for (int it = 0; it < 4; ++it){
      int e = it*256 + t, r = e >> 3, d4 = e & 7;
      float4 qv = qreg[it], kv = kreg[it];
      Qt[d4*4+0][r] = qv.x*SCALE; Qt[d4*4+1][r] = qv.y*SCALE;
      Qt[d4*4+2][r] = qv.z*SCALE; Qt[d4*4+3][r] = qv.w*SCALE;
      Kt[d4*4+0][r] = kv.x; Kt[d4*4+1][r] = kv.y;
      Kt[d4*4+2][r] = kv.z; Kt[d4*4+3][r] = kv.w;
    }
    __syncthreads();
    if (c < Dd/DC - 1){
      const int d0 = (c+1)*DC;
      #pragma unroll
      for (int it = 0; it < 4; ++it){
        int e = it*256 + t, r = e >> 3, d4 = e & 7;
        qreg[it] = ((const float4*)(Qb + (size_t)r*Dd + d0))[d4];
        kreg[it] = ((const float4*)(Kb + (size_t)r*Dd + d0))[d4];
      }
    }
    #pragma unroll 8
    for (int dd = 0; dd < DC; ++dd){
      float a[8], b[8];
      *(float4*)&a[0] = *(const float4*)&Qt[dd][ty*8];
      *(float4*)&a[4] = *(const float4*)&Qt[dd][ty*8+4];
      *(float4*)&b[0] = *(const float4*)&Kt[dd][tx*8];
      *(float4*)&b[4] = *(const float4*)&Kt[dd][tx*8+4];
      #pragma unroll
      for (int i = 0; i < 8; ++i)
        #pragma unroll
        for (int j = 0; j < 8; ++j)
          acc[i][j] += a[i]*b[j];
    }
    __syncthreads();
  }

  float* tbase = &g_E[(((size_t)h*16 + gp)*16 + jb) * (128*128)];
  #pragma unroll
  for (int i = 0; i < 8; ++i){
    const int r = ty*8 + i;
    float ev[8]; float s = 0.f;
    #pragma unroll
    for (int j = 0; j < 8; ++j){ ev[j] = __expf(acc[i][j]); s += ev[j]; }
    lsum[r][tx] = s;
    vf4 e0, e1;
    e0.x=ev[0]; e0.y=ev[1]; e0.z=ev[2]; e0.w=ev[3];
    e1.x=ev[4]; e1.y=ev[5]; e1.z=ev[6]; e1.w=ev[7];
    float* Ep = tbase + (size_t)r*128 + tx*8;
    __builtin_nontemporal_store(e0, (vf4*)Ep);
    __builtin_nontemporal_store(e1, (vf4*)(Ep+4));
  }
  __syncthreads();
  if (t < 128){
    float s = 0.f;
    #pragma unroll
    for (int x = 0; x < 16; ++x) s += lsum[t][x];
    g_lp[((size_t)h*Nn + R0 + t)*16 + jb] = s;
  }
}

// ---------------- Kernel 2a: parallel weighted colsum (6144 blocks, NT loads) ----------------
__global__ __launch_bounds__(256) void k2a_colsum(){
  const int bid = blockIdx.x;            // h*512 + g*16 + jb
  const int jb = bid & 15;
  const int g  = (bid >> 4) & 31;
  const int h  = bid >> 9;
  const int t = threadIdx.x;
  __shared__ float il_s[BMq];
  __shared__ float part[8][132];
  if (t < BMq){
    const float* lp = &g_lp[((size_t)h*Nn + g*BMq + t)*16];
    float s = 0.f;
    #pragma unroll
    for (int x = 0; x < 16; ++x) s += lp[x];
    il_s[t] = 1.0f / s;
  }
  __syncthreads();
  const int c4 = t & 31, rg = t >> 5;    // 32 f4-cols x 8 row-groups
  const float* slab = g_E + (((size_t)h*16 + (g >> 1))*16 + jb)*(128*128)
                          + (size_t)((g & 1)*64)*128;
  float4 s = {0.f,0.f,0.f,0.f};
  #pragma unroll
  for (int rr = 0; rr < 8; ++rr){
    const int r = rg*8 + rr;
    const float w = il_s[r];
    vf4 e = __builtin_nontemporal_load((const vf4*)&slab[(size_t)r*128 + c4*4]);
    s.x += e.x*w; s.y += e.y*w; s.z += e.z*w; s.w += e.w*w;
  }
  *(float4*)&part[rg][c4*4] = s;
  __syncthreads();
  if (t < 32){
    float4 acc = {0.f,0.f,0.f,0.f};
    #pragma unroll
    for (int u = 0; u < 8; ++u){
      float4 p = *(float4*)&part[u][t*4];
      acc.x += p.x; acc.y += p.y; acc.z += p.z; acc.w += p.w;
    }
    *(float4*)&g_bs[((size_t)h*QGg + g)*Nn + jb*128 + t*4] = acc;
  }
}

// ---------------- Kernel 2b: top-k + random + static window -> compacted key list ----------------
__global__ __launch_bounds__(256) void k2b_mask(){
  const int bid = blockIdx.x, g = bid % QGg, t = threadIdx.x;
  __shared__ float bsv[Nn];
  __shared__ int red[33];
  __shared__ int csel;
  const float* src = g_bs + (size_t)bid*Nn;
  float mine[8];
  {
    float4 a = *(const float4*)&src[t*4];
    float4 b = *(const float4*)&src[1024 + t*4];
    *(float4*)&bsv[t*4] = a;
    *(float4*)&bsv[1024 + t*4] = b;
    mine[0]=a.x; mine[1]=a.y; mine[2]=a.z; mine[3]=a.w;
    mine[4]=b.x; mine[5]=b.y; mine[6]=b.z; mine[7]=b.w;
  }
  if (t < 33) red[t] = 0;
  if (t == 0) csel = 0;
  __syncthreads();

  unsigned int k1a, k1b, k2a, k2b;
  tf2x32(0u, 1u, 0u, 0u, k1a, k1b);
  tf2x32(0u, 1u, 0u, 1u, k2a, k2b);

  // 192nd-largest via bitwise binary search (positive -> uint order)
  unsigned int prefix = 0u;
  for (int bit = 31; bit >= 0; --bit){
    unsigned int cand = prefix | (1u << bit);
    int c = 0;
    #pragma unroll
    for (int u = 0; u < 8; ++u)
      c += (__float_as_uint(mine[u]) >= cand) ? 1 : 0;
    #pragma unroll
    for (int off = 32; off > 0; off >>= 1) c += __shfl_down(c, off);
    if ((t & 63) == 0) atomicAdd(&red[bit], c);
    __syncthreads();
    if (red[bit] >= KSEL) prefix = cand;
  }
  {
    int cg = 0;
    #pragma unroll
    for (int u = 0; u < 8; ++u)
      cg += (__float_as_uint(mine[u]) > prefix) ? 1 : 0;
    #pragma unroll
    for (int off = 32; off > 0; off >>= 1) cg += __shfl_down(cg, off);
    if ((t & 63) == 0) atomicAdd(&red[32], cg);
  }
  __syncthreads();
  const int need = KSEL - red[32];   // ties taken lowest-index-first (jax top_k)

  const int lo = g*BMq + BMq/2 - 153;   // ws=int(0.15*2048)=307, ws//2=153
  const int hi = g*BMq + BMq/2 + 153;
  const int ssum = ((hi < Nn) ? hi : Nn) - ((lo > 0) ? lo : 0);
  const bool vqg = (ssum + KSEL) < Nn;  // always true at this config

  #pragma unroll
  for (int u = 0; u < 8; ++u){
    int j = (u < 4) ? (t*4 + u) : (1024 + t*4 + u - 4);
    unsigned int bu = __float_as_uint(mine[u]);
    bool topk = bu > prefix;
    if (!topk && bu == prefix){
      int tr = 0;
      for (int jj = 0; jj < j; ++jj)
        tr += (__float_as_uint(bsv[jj]) == prefix) ? 1 : 0;
      topk = (tr < need);
    }
    bool rnd = jax_rand01((unsigned)(bid*Nn + j), k1a, k1b, k2a, k2b);
    bool st  = (j >= lo) && (j < hi);
    bool selb = st || ((rnd || topk) && vqg);
    if (selb){
      int slot = atomicAdd(&csel, 1);
      g_sel[(size_t)bid*Nn + slot] = (unsigned short)j;
    }
  }
  __syncthreads();
  if (t == 0) g_cnt[bid] = csel;
}

// ---------------- Kernel 3: one-pass attention, XCD-swizzled, NO prefetch ----------------
__global__ __launch_bounds__(256) void k3_attn(const float* __restrict__ Q,
                                               const float* __restrict__ K,
                                               const float* __restrict__ V,
                                               const float* __restrict__ OC,
                                               float* __restrict__ out){
  const int bid0 = blockIdx.x;
  const int w    = (bid0 & 7)*96 + (bid0 >> 3);   // xcd-grouped work index
  const int half = w & 1;
  const int gg   = w >> 1;             // h*QGg + g
  const int h = gg / QGg, g = gg % QGg;
  const int t = threadIdx.x;
  __shared__ float q_s[32][Dd+4];
  __shared__ float kv_s[CK][Dd+4];
  __shared__ float s_s[32][CK+1];
  __shared__ float l_s[32];
  const int c = g_cnt[gg];
  const unsigned short* sel = g_sel + (size_t)gg*Nn;

  const float* qb = Q + ((size_t)h*Nn + (size_t)g*BMq + half*32)*Dd;
  #pragma unroll
  for (int it = 0; it < 4; ++it){
    int e = it*256 + t;                 // 1024 float4s = 32 rows x 32 f4
    int row = e >> 5, c4 = e & 31;
    float4 vq = ((const float4*)qb)[e];
    float4 sv; sv.x = vq.x*SCALE; sv.y = vq.y*SCALE; sv.z = vq.z*SCALE; sv.w = vq.w*SCALE;
    *(float4*)&q_s[row][c4*4] = sv;
  }
  if (t < 32) l_s[t] = 0.0f;
  __syncthreads();

  const int rt = t & 15, kcol = (t >> 4)*2;
  const int d0 = (t >> 4)*8;           // PV column group
  float acc2[2][8] = {};

  for (int c0 = 0; c0 < c; c0 += CK){
    const int cc = ((c - c0) < CK) ? (c - c0) : CK;
    // gather K chunk
    #pragma unroll
    for (int it = 0; it < 4; ++it){
      int e = it*256 + t, row = e >> 5, c4 = e & 31;
      int j = (row < cc) ? (int)sel[c0 + row] : 0;
      *(float4*)&kv_s[row][c4*4] = ((const float4*)(K + ((size_t)h*Nn + j)*Dd))[c4];
    }
    __syncthreads();
    float a00=0.f, a01=0.f, a10=0.f, a11=0.f;
    #pragma unroll 8
    for (int d = 0; d < Dd; d += 4){
      float4 k0 = *(const float4*)&kv_s[kcol][d];
      float4 k1 = *(const float4*)&kv_s[kcol+1][d];
      float4 q0 = *(const float4*)&q_s[rt][d];
      float4 q1 = *(const float4*)&q_s[rt+16][d];
      a00 += q0.x*k0.x + q0.y*k0.y + q0.z*k0.z + q0.w*k0.w;
      a01 += q0.x*k1.x + q0.y*k1.y + q0.z*k1.z + q0.w*k1.w;
      a10 += q1.x*k0.x + q1.y*k0.y + q1.z*k0.z + q1.w*k0.w;
      a11 += q1.x*k1.x + q1.y*k1.y + q1.z*k1.z + q1.w*k1.w;
    }
    s_s[rt   ][kcol  ] = (kcol   < cc) ? __expf(a00) : 0.f;
    s_s[rt   ][kcol+1] = (kcol+1 < cc) ? __expf(a01) : 0.f;
    s_s[rt+16][kcol  ] = (kcol   < cc) ? __expf(a10) : 0.f;
    s_s[rt+16][kcol+1] = (kcol+1 < cc) ? __expf(a11) : 0.f;
    __syncthreads();
    if (t < 32){
      float s = 0.f;
      #pragma unroll
      for (int c2 = 0; c2 < CK; ++c2) s += s_s[t][c2];
      l_s[t] += s;
    }
    // gather V chunk (overwrites kv_s; QK readers already past barrier)
    #pragma unroll
    for (int it = 0; it < 4; ++it){
      int e = it*256 + t, row = e >> 5, c4 = e & 31;
      int j = (row < cc) ? (int)sel[c0 + row] : 0;
      *(float4*)&kv_s[row][c4*4] = ((const float4*)(V + ((size_t)h*Nn + j)*Dd))[c4];
    }
    __syncthreads();
    for (int c2 = 0; c2 < cc; ++c2){
      float p0 = s_s[rt][c2], p1 = s_s[rt+16][c2];
      float4 va = *(const float4*)&kv_s[c2][d0];
      float4 vb = *(const float4*)&kv_s[c2][d0+4];
      acc2[0][0] += p0*va.x; acc2[0][1] += p0*va.y;
      acc2[0][2] += p0*va.z; acc2[0][3] += p0*va.w;
      acc2[0][4] += p0*vb.x; acc2[0][5] += p0*vb.y;
      acc2[0][6] += p0*vb.z; acc2[0][7] += p0*vb.w;
      acc2[1][0] += p1*va.x; acc2[1][1] += p1*va.y;
      acc2[1][2] += p1*va.z; acc2[1][3] += p1*va.w;
      acc2[1][4] += p1*vb.x; acc2[1][5] += p1*vb.y;
      acc2[1][6] += p1*vb.z; acc2[1][7] += p1*vb.w;
    }
    __syncthreads();
  }

  if (t < 32) l_s[t] = 1.0f / l_s[t];
  __syncthreads();

  #pragma unroll
  for (int rr = 0; rr < 2; ++rr){
    const int r = rr*16 + rt;
    const float il = l_s[r];
    size_t o = ((size_t)h*Nn + (size_t)g*BMq + half*32 + r)*Dd + d0;
    float4 ca = *(const float4*)(OC + o);
    float4 cb = *(const float4*)(OC + o + 4);
    float4 ra, rb;
    ra.x = acc2[rr][0]*il + ca.x; ra.y = acc2[rr][1]*il + ca.y;
    ra.z = acc2[rr][2]*il + ca.z; ra.w = acc2[rr][3]*il + ca.w;
    rb.x = acc2[rr][4]*il + cb.x; rb.y = acc2[rr][5]*il + cb.y;
    rb.z = acc2[rr][6]*il + cb.z; rb.w = acc2[rr][7]*il + cb.w;
    *(float4*)(out + o)     = ra;
    *(float4*)(out + o + 4) = rb;
  }
}

extern "C" void kernel_launch(void* const* d_in, const int* in_sizes, int n_in,
                              void* d_out, int out_size, void* d_ws, size_t ws_size,
                              hipStream_t stream) {
  (void)in_sizes; (void)n_in; (void)out_size; (void)d_ws; (void)ws_size;
  const float* Q  = (const float*)d_in[0];
  const float* K  = (const float*)d_in[1];
  const float* V  = (const float*)d_in[2];
  const float* OC = (const float*)d_in[3];
  float* out = (float*)d_out;
  hipLaunchKernelGGL(k1a_scores, dim3(Hh*16*16),    dim3(256), 0, stream, Q, K);
  hipLaunchKernelGGL(k2a_colsum, dim3(Hh*QGg*16),   dim3(256), 0, stream);
  hipLaunchKernelGGL(k2b_mask,   dim3(Hh*QGg),      dim3(256), 0, stream);
  hipLaunchKernelGGL(k3_attn,    dim3(Hh*QGg*2),    dim3(256), 0, stream, Q, K, V, OC, out);
}

// Round 18
// 490.791 us; speedup vs baseline: 1.3059x; 1.0982x over previous
//
#include <hip/hip_runtime.h>
#include <math.h>

// SparseDiffAttn: B=1,H=12,N=2048,D=128, BM=64, top-k=192, static window [c-153,c+153),
// random keys via modern-JAX randint under jax_threefry_partitionable=True:
//   k1 = tf((0,1),(0,0)), k2 = tf((0,1),(0,1))        [fold-like split]
//   bits(k,i) = b1^b2 with (b1,b2) = tf(k,(0,i))      [partitionable random_bits]
//   offset = ((hi%100)*96 + lo%100) % 100; rnd <=> offset==0
// PRECISION: selection robust to ~1e-6 rel (fp32==fp64 masks) but NOT fp16-E (R10, 5e-4).
// Split-fp16 MFMA QK (hi·hi + hi·lo + lo·hi) err ~1e-7 rel — inside the certified band.
// RULES LEARNED: (a) no register prefetch in k3 — R8/R13: destroys L2 reuse; barrier
// lockstep IS the reuse mechanism. (b) E materialization beats 2x QK recompute (R12).
// (c) k3 XCD swizzle: FETCH 157->28MB. (d) E-stream ~1.1TB/s is invariant to layout
// (R7/R9/R14), occupancy (R15), and cache policy (R17 NT) — treat as floor.
// THIS ROUND: k1a QK moved to MFMA (split-fp16, global-direct fragments, zero LDS/barriers).
constexpr int Hh   = 12;
constexpr int Nn   = 2048;
constexpr int Dd   = 128;
constexpr int BMq  = 64;
constexpr int QGg  = 32;            // Nn/BMq
constexpr int KSEL = 192;           // 64 * round(0.1*2048/64)
constexpr int CK   = 32;            // key chunk (k3)
constexpr float SCALE = 0.08838834764831845f;  // 1/sqrt(128)

typedef _Float16 v8h __attribute__((ext_vector_type(8)));   // MFMA A/B frag (4 VGPRs)
typedef float    v4f __attribute__((ext_vector_type(4)));   // MFMA C/D frag

// persistent scratch (fully rewritten every launch before any read)
// g_E tile-blocked: tile (h,gp,jb) = 128x128 floats contiguous, row-major inside.
__device__ float          g_E [(size_t)Hh*16*16*128*128];   // 201 MB
__device__ float          g_lp[(size_t)Hh*Nn*16];           // per-jb partial row sums
__device__ float          g_bs[(size_t)Hh*QGg*Nn];          // colsum scores (3 MB)
__device__ unsigned short g_sel[Hh*QGg*Nn];
__device__ int            g_cnt[Hh*QGg];

__device__ __forceinline__ unsigned int rotl32(unsigned int x, int n){
  return (x << n) | (x >> (32 - n));
}

// threefry2x32, 20 rounds, arbitrary key
__device__ __forceinline__ void tf2x32(unsigned int k0, unsigned int k1,
                                       unsigned int x0, unsigned int x1,
                                       unsigned int &o0, unsigned int &o1){
  const unsigned int ks2 = 0x1BD11BDAu ^ k0 ^ k1;
  x0 += k0; x1 += k1;
  x0 += x1; x1 = rotl32(x1,13); x1 ^= x0;
  x0 += x1; x1 = rotl32(x1,15); x1 ^= x0;
  x0 += x1; x1 = rotl32(x1,26); x1 ^= x0;
  x0 += x1; x1 = rotl32(x1, 6); x1 ^= x0;
  x0 += k1; x1 += ks2 + 1u;
  x0 += x1; x1 = rotl32(x1,17); x1 ^= x0;
  x0 += x1; x1 = rotl32(x1,29); x1 ^= x0;
  x0 += x1; x1 = rotl32(x1,16); x1 ^= x0;
  x0 += x1; x1 = rotl32(x1,24); x1 ^= x0;
  x0 += ks2; x1 += k0 + 2u;
  x0 += x1; x1 = rotl32(x1,13); x1 ^= x0;
  x0 += x1; x1 = rotl32(x1,15); x1 ^= x0;
  x0 += x1; x1 = rotl32(x1,26); x1 ^= x0;
  x0 += x1; x1 = rotl32(x1, 6); x1 ^= x0;
  x0 += k0; x1 += k1 + 3u;
  x0 += x1; x1 = rotl32(x1,17); x1 ^= x0;
  x0 += x1; x1 = rotl32(x1,29); x1 ^= x0;
  x0 += x1; x1 = rotl32(x1,16); x1 ^= x0;
  x0 += x1; x1 = rotl32(x1,24); x1 ^= x0;
  x0 += k1; x1 += ks2 + 4u;
  x0 += x1; x1 = rotl32(x1,13); x1 ^= x0;
  x0 += x1; x1 = rotl32(x1,15); x1 ^= x0;
  x0 += x1; x1 = rotl32(x1,26); x1 ^= x0;
  x0 += x1; x1 = rotl32(x1, 6); x1 ^= x0;
  x0 += ks2; x1 += k0 + 5u;
  o0 = x0; o1 = x1;
}

// partitionable-threefry randint(key(1), ..., 0, 100) == 0 for flat element idx
__device__ __forceinline__ bool jax_rand01(unsigned int idx,
                                           unsigned int k1a, unsigned int k1b,
                                           unsigned int k2a, unsigned int k2b){
  unsigned int h0, h1, l0, l1;
  tf2x32(k1a, k1b, 0u, idx, h0, h1);
  tf2x32(k2a, k2b, 0u, idx, l0, l1);
  unsigned int h = h0 ^ h1;
  unsigned int l = l0 ^ l1;
  unsigned int off = ((h % 100u) * 96u + (l % 100u)) % 100u;
  return off == 0u;
}

// ---------------- Kernel 1a: MFMA split-fp16 E=__expf(QK^T*scale), tile-blocked ----------------
// 128x128 tile per block, 4 waves x (2 tile-rows x 8 tile-cols) of 16x16x32_f16 MFMAs.
// A layout: lane holds A[m=lane&15][k=quad*8+j]; B: B[n=lane&15][k=quad*8+j];
// D layout (HW-verified m89/m91): col=lane&15, row=quad*4+reg. No LDS, no barriers.
__global__ __launch_bounds__(256) void k1a_scores(const float* __restrict__ Q,
                                                  const float* __restrict__ K){
  const int bid = blockIdx.x;
  const int jb = bid & 15, gp = (bid >> 4) & 15, h = bid >> 8;
  const int t = threadIdx.x;
  const int wv = t >> 6, ln = t & 63;
  const int nidx = ln & 15, quad = ln >> 4;
  const int R0 = gp*128, J0 = jb*128;

  v4f acc[2][8];
  #pragma unroll
  for (int tr = 0; tr < 2; ++tr)
    #pragma unroll
    for (int tc = 0; tc < 8; ++tc)
      acc[tr][tc] = (v4f){0.f, 0.f, 0.f, 0.f};

  for (int kc = 0; kc < 4; ++kc){
    const int dofs = kc*32 + quad*8;
    v8h ahi[2], alo[2];
    #pragma unroll
    for (int tr = 0; tr < 2; ++tr){
      const float* qp = Q + ((size_t)h*Nn + R0 + (wv*2+tr)*16 + nidx)*Dd + dofs;
      float4 qa = *(const float4*)qp, qb = *(const float4*)(qp+4);
      float xs[8] = {qa.x,qa.y,qa.z,qa.w, qb.x,qb.y,qb.z,qb.w};
      #pragma unroll
      for (int j = 0; j < 8; ++j){
        float x = xs[j]*SCALE;
        _Float16 hi = (_Float16)x;
        ahi[tr][j] = hi;
        alo[tr][j] = (_Float16)(x - (float)hi);
      }
    }
    v8h bhi[8], blo[8];
    #pragma unroll
    for (int tc = 0; tc < 8; ++tc){
      const float* kp = K + ((size_t)h*Nn + J0 + tc*16 + nidx)*Dd + dofs;
      float4 ka = *(const float4*)kp, kb = *(const float4*)(kp+4);
      float xs[8] = {ka.x,ka.y,ka.z,ka.w, kb.x,kb.y,kb.z,kb.w};
      #pragma unroll
      for (int j = 0; j < 8; ++j){
        float x = xs[j];
        _Float16 hi = (_Float16)x;
        bhi[tc][j] = hi;
        blo[tc][j] = (_Float16)(x - (float)hi);
      }
    }
    #pragma unroll
    for (int tr = 0; tr < 2; ++tr)
      #pragma unroll
      for (int tc = 0; tc < 8; ++tc){
        acc[tr][tc] = __builtin_amdgcn_mfma_f32_16x16x32_f16(ahi[tr], bhi[tc], acc[tr][tc], 0, 0, 0);
        acc[tr][tc] = __builtin_amdgcn_mfma_f32_16x16x32_f16(ahi[tr], blo[tc], acc[tr][tc], 0, 0, 0);
        acc[tr][tc] = __builtin_amdgcn_mfma_f32_16x16x32_f16(alo[tr], bhi[tc], acc[tr][tc], 0, 0, 0);
      }
  }

  // epilogue: exp, E store (tile-blocked), shfl-reduced row sums -> g_lp
  float* tbase = &g_E[(((size_t)h*16 + gp)*16 + jb) * (128*128)];
  #pragma unroll
  for (int tr = 0; tr < 2; ++tr){
    float rs[4] = {0.f, 0.f, 0.f, 0.f};
    #pragma unroll
    for (int tc = 0; tc < 8; ++tc){
      #pragma unroll
      for (int r = 0; r < 4; ++r){
        float ev = __expf(acc[tr][tc][r]);
        const int row = (wv*2+tr)*16 + quad*4 + r;
        tbase[(size_t)row*128 + tc*16 + nidx] = ev;
        rs[r] += ev;
      }
    }
    #pragma unroll
    for (int r = 0; r < 4; ++r){
      float v = rs[r];
      v += __shfl_xor(v, 1);
      v += __shfl_xor(v, 2);
      v += __shfl_xor(v, 4);
      v += __shfl_xor(v, 8);
      rs[r] = v;
    }
    if (nidx == 0){
      #pragma unroll
      for (int r = 0; r < 4; ++r){
        const int row = (wv*2+tr)*16 + quad*4 + r;
        g_lp[((size_t)h*Nn + R0 + row)*16 + jb] = rs[r];
      }
    }
  }
}

// ---------------- Kernel 2a: parallel weighted colsum (6144 blocks) ----------------
__global__ __launch_bounds__(256) void k2a_colsum(){
  const int bid = blockIdx.x;            // h*512 + g*16 + jb
  const int jb = bid & 15;
  const int g  = (bid >> 4) & 31;
  const int h  = bid >> 9;
  const int t = threadIdx.x;
  __shared__ float il_s[BMq];
  __shared__ float part[8][132];
  if (t < BMq){
    const float* lp = &g_lp[((size_t)h*Nn + g*BMq + t)*16];
    float s = 0.f;
    #pragma unroll
    for (int x = 0; x < 16; ++x) s += lp[x];
    il_s[t] = 1.0f / s;
  }
  __syncthreads();
  const int c4 = t & 31, rg = t >> 5;    // 32 f4-cols x 8 row-groups
  const float* slab = g_E + (((size_t)h*16 + (g >> 1))*16 + jb)*(128*128)
                          + (size_t)((g & 1)*64)*128;
  float4 s = {0.f,0.f,0.f,0.f};
  #pragma unroll
  for (int rr = 0; rr < 8; ++rr){
    const int r = rg*8 + rr;
    const float w = il_s[r];
    float4 e = *(const float4*)&slab[(size_t)r*128 + c4*4];
    s.x += e.x*w; s.y += e.y*w; s.z += e.z*w; s.w += e.w*w;
  }
  *(float4*)&part[rg][c4*4] = s;
  __syncthreads();
  if (t < 32){
    float4 acc = {0.f,0.f,0.f,0.f};
    #pragma unroll
    for (int u = 0; u < 8; ++u){
      float4 p = *(float4*)&part[u][t*4];
      acc.x += p.x; acc.y += p.y; acc.z += p.z; acc.w += p.w;
    }
    *(float4*)&g_bs[((size_t)h*QGg + g)*Nn + jb*128 + t*4] = acc;
  }
}

// ---------------- Kernel 2b: top-k + random + static window -> compacted key list ----------------
__global__ __launch_bounds__(256) void k2b_mask(){
  const int bid = blockIdx.x, g = bid % QGg, t = threadIdx.x;
  __shared__ float bsv[Nn];
  __shared__ int red[33];
  __shared__ int csel;
  const float* src = g_bs + (size_t)bid*Nn;
  float mine[8];
  {
    float4 a = *(const float4*)&src[t*4];
    float4 b = *(const float4*)&src[1024 + t*4];
    *(float4*)&bsv[t*4] = a;
    *(float4*)&bsv[1024 + t*4] = b;
    mine[0]=a.x; mine[1]=a.y; mine[2]=a.z; mine[3]=a.w;
    mine[4]=b.x; mine[5]=b.y; mine[6]=b.z; mine[7]=b.w;
  }
  if (t < 33) red[t] = 0;
  if (t == 0) csel = 0;
  __syncthreads();

  unsigned int k1a, k1b, k2a, k2b;
  tf2x32(0u, 1u, 0u, 0u, k1a, k1b);
  tf2x32(0u, 1u, 0u, 1u, k2a, k2b);

  // 192nd-largest via bitwise binary search (positive -> uint order)
  unsigned int prefix = 0u;
  for (int bit = 31; bit >= 0; --bit){
    unsigned int cand = prefix | (1u << bit);
    int c = 0;
    #pragma unroll
    for (int u = 0; u < 8; ++u)
      c += (__float_as_uint(mine[u]) >= cand) ? 1 : 0;
    #pragma unroll
    for (int off = 32; off > 0; off >>= 1) c += __shfl_down(c, off);
    if ((t & 63) == 0) atomicAdd(&red[bit], c);
    __syncthreads();
    if (red[bit] >= KSEL) prefix = cand;
  }
  {
    int cg = 0;
    #pragma unroll
    for (int u = 0; u < 8; ++u)
      cg += (__float_as_uint(mine[u]) > prefix) ? 1 : 0;
    #pragma unroll
    for (int off = 32; off > 0; off >>= 1) cg += __shfl_down(cg, off);
    if ((t & 63) == 0) atomicAdd(&red[32], cg);
  }
  __syncthreads();
  const int need = KSEL - red[32];   // ties taken lowest-index-first (jax top_k)

  const int lo = g*BMq + BMq/2 - 153;   // ws=int(0.15*2048)=307, ws//2=153
  const int hi = g*BMq + BMq/2 + 153;
  const int ssum = ((hi < Nn) ? hi : Nn) - ((lo > 0) ? lo : 0);
  const bool vqg = (ssum + KSEL) < Nn;  // always true at this config

  #pragma unroll
  for (int u = 0; u < 8; ++u){
    int j = (u < 4) ? (t*4 + u) : (1024 + t*4 + u - 4);
    unsigned int bu = __float_as_uint(mine[u]);
    bool topk = bu > prefix;
    if (!topk && bu == prefix){
      int tr = 0;
      for (int jj = 0; jj < j; ++jj)
        tr += (__float_as_uint(bsv[jj]) == prefix) ? 1 : 0;
      topk = (tr < need);
    }
    bool rnd = jax_rand01((unsigned)(bid*Nn + j), k1a, k1b, k2a, k2b);
    bool st  = (j >= lo) && (j < hi);
    bool selb = st || ((rnd || topk) && vqg);
    if (selb){
      int slot = atomicAdd(&csel, 1);
      g_sel[(size_t)bid*Nn + slot] = (unsigned short)j;
    }
  }
  __syncthreads();
  if (t == 0) g_cnt[bid] = csel;
}

// ---------------- Kernel 3: one-pass attention, XCD-swizzled, NO prefetch ----------------
__global__ __launch_bounds__(256) void k3_attn(const float* __restrict__ Q,
                                               const float* __restrict__ K,
                                               const float* __restrict__ V,
                                               const float* __restrict__ OC,
                                               float* __restrict__ out){
  const int bid0 = blockIdx.x;
  const int w    = (bid0 & 7)*96 + (bid0 >> 3);   // xcd-grouped work index
  const int half = w & 1;
  const int gg   = w >> 1;             // h*QGg + g
  const int h = gg / QGg, g = gg % QGg;
  const int t = threadIdx.x;
  __shared__ float q_s[32][Dd+4];
  __shared__ float kv_s[CK][Dd+4];
  __shared__ float s_s[32][CK+1];
  __shared__ float l_s[32];
  const int c = g_cnt[gg];
  const unsigned short* sel = g_sel + (size_t)gg*Nn;

  const float* qb = Q + ((size_t)h*Nn + (size_t)g*BMq + half*32)*Dd;
  #pragma unroll
  for (int it = 0; it < 4; ++it){
    int e = it*256 + t;                 // 1024 float4s = 32 rows x 32 f4
    int row = e >> 5, c4 = e & 31;
    float4 vq = ((const float4*)qb)[e];
    float4 sv; sv.x = vq.x*SCALE; sv.y = vq.y*SCALE; sv.z = vq.z*SCALE; sv.w = vq.w*SCALE;
    *(float4*)&q_s[row][c4*4] = sv;
  }
  if (t < 32) l_s[t] = 0.0f;
  __syncthreads();

  const int rt = t & 15, kcol = (t >> 4)*2;
  const int d0 = (t >> 4)*8;           // PV column group
  float acc2[2][8] = {};

  for (int c0 = 0; c0 < c; c0 += CK){
    const int cc = ((c - c0) < CK) ? (c - c0) : CK;
    // gather K chunk
    #pragma unroll
    for (int it = 0; it < 4; ++it){
      int e = it*256 + t, row = e >> 5, c4 = e & 31;
      int j = (row < cc) ? (int)sel[c0 + row] : 0;
      *(float4*)&kv_s[row][c4*4] = ((const float4*)(K + ((size_t)h*Nn + j)*Dd))[c4];
    }
    __syncthreads();
    float a00=0.f, a01=0.f, a10=0.f, a11=0.f;
    #pragma unroll 8
    for (int d = 0; d < Dd; d += 4){
      float4 k0 = *(const float4*)&kv_s[kcol][d];
      float4 k1 = *(const float4*)&kv_s[kcol+1][d];
      float4 q0 = *(const float4*)&q_s[rt][d];
      float4 q1 = *(const float4*)&q_s[rt+16][d];
      a00 += q0.x*k0.x + q0.y*k0.y + q0.z*k0.z + q0.w*k0.w;
      a01 += q0.x*k1.x + q0.y*k1.y + q0.z*k1.z + q0.w*k1.w;
      a10 += q1.x*k0.x + q1.y*k0.y + q1.z*k0.z + q1.w*k0.w;
      a11 += q1.x*k1.x + q1.y*k1.y + q1.z*k1.z + q1.w*k1.w;
    }
    s_s[rt   ][kcol  ] = (kcol   < cc) ? __expf(a00) : 0.f;
    s_s[rt   ][kcol+1] = (kcol+1 < cc) ? __expf(a01) : 0.f;
    s_s[rt+16][kcol  ] = (kcol   < cc) ? __expf(a10) : 0.f;
    s_s[rt+16][kcol+1] = (kcol+1 < cc) ? __expf(a11) : 0.f;
    __syncthreads();
    if (t < 32){
      float s = 0.f;
      #pragma unroll
      for (int c2 = 0; c2 < CK; ++c2) s += s_s[t][c2];
      l_s[t] += s;
    }
    // gather V chunk (overwrites kv_s; QK readers already past barrier)
    #pragma unroll
    for (int it = 0; it < 4; ++it){
      int e = it*256 + t, row = e >> 5, c4 = e & 31;
      int j = (row < cc) ? (int)sel[c0 + row] : 0;
      *(float4*)&kv_s[row][c4*4] = ((const float4*)(V + ((size_t)h*Nn + j)*Dd))[c4];
    }
    __syncthreads();
    for (int c2 = 0; c2 < cc; ++c2){
      float p0 = s_s[rt][c2], p1 = s_s[rt+16][c2];
      float4 va = *(const float4*)&kv_s[c2][d0];
      float4 vb = *(const float4*)&kv_s[c2][d0+4];
      acc2[0][0] += p0*va.x; acc2[0][1] += p0*va.y;
      acc2[0][2] += p0*va.z; acc2[0][3] += p0*va.w;
      acc2[0][4] += p0*vb.x; acc2[0][5] += p0*vb.y;
      acc2[0][6] += p0*vb.z; acc2[0][7] += p0*vb.w;
      acc2[1][0] += p1*va.x; acc2[1][1] += p1*va.y;
      acc2[1][2] += p1*va.z; acc2[1][3] += p1*va.w;
      acc2[1][4] += p1*vb.x; acc2[1][5] += p1*vb.y;
      acc2[1][6] += p1*vb.z; acc2[1][7] += p1*vb.w;
    }
    __syncthreads();
  }

  if (t < 32) l_s[t] = 1.0f / l_s[t];
  __syncthreads();

  #pragma unroll
  for (int rr = 0; rr < 2; ++rr){
    const int r = rr*16 + rt;
    const float il = l_s[r];
    size_t o = ((size_t)h*Nn + (size_t)g*BMq + half*32 + r)*Dd + d0;
    float4 ca = *(const float4*)(OC + o);
    float4 cb = *(const float4*)(OC + o + 4);
    float4 ra, rb;
    ra.x = acc2[rr][0]*il + ca.x; ra.y = acc2[rr][1]*il + ca.y;
    ra.z = acc2[rr][2]*il + ca.z; ra.w = acc2[rr][3]*il + ca.w;
    rb.x = acc2[rr][4]*il + cb.x; rb.y = acc2[rr][5]*il + cb.y;
    rb.z = acc2[rr][6]*il + cb.z; rb.w = acc2[rr][7]*il + cb.w;
    *(float4*)(out + o)     = ra;
    *(float4*)(out + o + 4) = rb;
  }
}

extern "C" void kernel_launch(void* const* d_in, const int* in_sizes, int n_in,
                              void* d_out, int out_size, void* d_ws, size_t ws_size,
                              hipStream_t stream) {
  (void)in_sizes; (void)n_in; (void)out_size; (void)d_ws; (void)ws_size;
  const float* Q  = (const float*)d_in[0];
  const float* K  = (const float*)d_in[1];
  const float* V  = (const float*)d_in[2];
  const float* OC = (const float*)d_in[3];
  float* out = (float*)d_out;
  hipLaunchKernelGGL(k1a_scores, dim3(Hh*16*16),    dim3(256), 0, stream, Q, K);
  hipLaunchKernelGGL(k2a_colsum, dim3(Hh*QGg*16),   dim3(256), 0, stream);
  hipLaunchKernelGGL(k2b_mask,   dim3(Hh*QGg),      dim3(256), 0, stream);
  hipLaunchKernelGGL(k3_attn,    dim3(Hh*QGg*2),    dim3(256), 0, stream, Q, K, V, OC, out);
}